// Round 9
// baseline (254.353 us; speedup 1.0000x reference)
//
#include <hip/hip_runtime.h>
#include <hip/hip_bf16.h>
#include <math.h>

#define TOK 8192       // B*S
#define DIM 256
#define SEQ 1024
#define NH 8
#define FFD 1024
#define NL 2
#define VOCAB 32000
#define QKSTRIDE 2097152   // elems between Q and K head-major blocks

typedef short bf16x8 __attribute__((ext_vector_type(8)));
typedef float f32x4 __attribute__((ext_vector_type(4)));

__device__ __forceinline__ ushort f2bf(float f) {
  union { float f; uint32_t u; } v; v.f = f;
  uint32_t r = v.u + 0x7FFFu + ((v.u >> 16) & 1u);
  return (ushort)(r >> 16);
}

__device__ __forceinline__ float exp2_n(float x) {
  float r; asm("v_exp_f32 %0, %1" : "=v"(r) : "v"(x)); return r;
}

__device__ __forceinline__ uint32_t cvtpk(float lo, float hi) {
  uint32_t r; asm("v_cvt_pk_bf16_f32 %0, %1, %2" : "=v"(r) : "v"(lo), "v"(hi));
  return r;
}

__device__ __forceinline__ void gload_lds16(const ushort* gp, ushort* lp) {
  __builtin_amdgcn_global_load_lds(
      (const __attribute__((address_space(1))) void*)gp,
      (__attribute__((address_space(3))) void*)lp, 16, 0, 0);
}

// ---------------- embedding + ngram + tfidf bias + fused layer-0 LN ----------------
__global__ __launch_bounds__(256) void embed_ln_kernel(
    const int* __restrict__ ids, const int* __restrict__ ngram_ids,
    const float* __restrict__ tfidf, const float* __restrict__ emb,
    const float* __restrict__ pos, const float* __restrict__ bucket,
    const float* __restrict__ alpha, const float* __restrict__ g1,
    const float* __restrict__ be1,
    float* __restrict__ x, ushort* __restrict__ x2b, float* __restrict__ bm2)
{
  __shared__ int ngs[12];
  __shared__ float red[2][4];
  const int t = blockIdx.x;
  const int id = ids[t];
  int idc = id; if (idc < 0) idc = 0; if (idc > VOCAB-1) idc = VOCAB-1;
  if (threadIdx.x < 12) ngs[threadIdx.x] = ngram_ids[idc*12 + threadIdx.x];
  if (threadIdx.x == 0) {
    const float tf = tfidf[idc];
    const bool msk = (id == 0);
    const float l2e = 1.4426950408889634f;
    bm2[t]       = msk ? -1e30f : tf * alpha[0] * l2e;
    bm2[TOK + t] = msk ? -1e30f : tf * alpha[1] * l2e;
  }
  __syncthreads();
  const int d = threadIdx.x;
  const int s = t & (SEQ - 1);
  float v = emb[(size_t)id*DIM + d] + pos[s*DIM + d];
  float sum = 0.f; int cnt = 0;
  #pragma unroll
  for (int g = 0; g < 12; ++g) {
    const int ng = ngs[g];
    if (ng != 0) { sum += bucket[(size_t)ng*DIM + d]; cnt++; }
  }
  v += sum / fmaxf((float)cnt, 1.0f);
  x[(size_t)t*DIM + d] = v;
  // fused LN (layer 0, ln1)
  const int wave = d >> 6, lane = d & 63;
  float sm = v;
  #pragma unroll
  for (int o = 32; o >= 1; o >>= 1) sm += __shfl_xor(sm, o);
  if (lane == 0) red[0][wave] = sm;
  __syncthreads();
  const float mean = (red[0][0]+red[0][1]+red[0][2]+red[0][3]) * (1.f/256.f);
  const float dv = v - mean;
  float q = dv * dv;
  #pragma unroll
  for (int o = 32; o >= 1; o >>= 1) q += __shfl_xor(q, o);
  if (lane == 0) red[1][wave] = q;
  __syncthreads();
  const float var = (red[1][0]+red[1][1]+red[1][2]+red[1][3]) * (1.f/256.f);
  const float rs = rsqrtf(var + 1e-5f);
  x2b[(size_t)t*DIM + d] = f2bf(dv*rs*g1[d] + be1[d]);
}

// ---------------- layernorm -> bf16 ----------------
__global__ __launch_bounds__(256) void ln_bf16(
    const float* __restrict__ x, const float* __restrict__ g,
    const float* __restrict__ b, ushort* __restrict__ y)
{
  const int wave = threadIdx.x >> 6, lane = threadIdx.x & 63;
  const int row = blockIdx.x * 4 + wave;
  const float* xr = x + (size_t)row * DIM;
  float4 v = *reinterpret_cast<const float4*>(xr + lane*4);
  float s = v.x + v.y + v.z + v.w;
  #pragma unroll
  for (int o = 32; o >= 1; o >>= 1) s += __shfl_xor(s, o);
  const float mean = s * (1.f/256.f);
  const float dx0 = v.x-mean, dx1 = v.y-mean, dx2 = v.z-mean, dx3 = v.w-mean;
  float q = dx0*dx0 + dx1*dx1 + dx2*dx2 + dx3*dx3;
  #pragma unroll
  for (int o = 32; o >= 1; o >>= 1) q += __shfl_xor(q, o);
  const float rs = rsqrtf(q * (1.f/256.f) + 1e-5f);
  float4 gv = *reinterpret_cast<const float4*>(g + lane*4);
  float4 bv = *reinterpret_cast<const float4*>(b + lane*4);
  ushort4 o4;
  o4.x = f2bf(dx0*rs*gv.x + bv.x);
  o4.y = f2bf(dx1*rs*gv.y + bv.y);
  o4.z = f2bf(dx2*rs*gv.z + bv.z);
  o4.w = f2bf(dx3*rs*gv.w + bv.w);
  *reinterpret_cast<ushort4*>(y + (size_t)row*DIM + lane*4) = o4;
}

// ---------------- weight transpose + bf16: f32 [K][N] -> bf16 [N][K] ----------------
struct TDesc { const float* src; ushort* dst; int K; int N; };
struct TDescs { TDesc d[12]; };

__global__ __launch_bounds__(256) void transpose_conv(TDescs descs)
{
  const TDesc t = descs.d[blockIdx.z];
  const int k0 = blockIdx.x * 32, n0 = blockIdx.y * 32;
  if (k0 >= t.K || n0 >= t.N) return;
  __shared__ float tile[32][33];
  const int r = threadIdx.x >> 5, cc = threadIdx.x & 31;
  #pragma unroll
  for (int i = 0; i < 4; ++i)
    tile[r + i*8][cc] = t.src[(size_t)(k0 + r + i*8)*t.N + n0 + cc];
  __syncthreads();
  #pragma unroll
  for (int i = 0; i < 4; ++i)
    t.dst[(size_t)(n0 + r + i*8)*t.K + k0 + cc] = f2bf(tile[cc][r + i*8]);
}

// ---------------- full-K 128x128 GEMM (K=256): whole K-strip in LDS, ONE barrier ----------------
// 4 waves 2x2, each 64x64 (4x4 frags). LDS layout [kstep][row][32] (64B rows, conflict-free).
// MODE 1: relu + bf16 out (stride NDIM);
// MODE 3: qkv -> Q,K head-major (Cout, +QKSTRIDE for K); V permuted into vtb.
template<int NDIM, int MODE>
__global__ __launch_bounds__(256) void gemm_fullk(
    const ushort* __restrict__ A, const ushort* __restrict__ Bw,
    const float* __restrict__ bias0, const float* __restrict__ bias1,
    const float* __restrict__ bias2, void* __restrict__ Cout,
    ushort* __restrict__ vtb)
{
  __shared__ ushort Al[8][128][32];
  __shared__ ushort Bl[8][128][32];
  const int bm = blockIdx.y * 128, bn = blockIdx.x * 128;
  const int tid = threadIdx.x, w = tid >> 6, lane = tid & 63;
  const int wm = w >> 1, wn = w & 1;
  const int g = lane >> 4, c = lane & 15;
  const f32x4 fzero = {0.f, 0.f, 0.f, 0.f};

  #pragma unroll
  for (int p = 0; p < 16; ++p) {
    const int i = p*256 + tid;               // [0,4096) 16B chunks
    const int ks = i >> 9, row = (i >> 2) & 127, c8 = (i & 3) * 8;
    gload_lds16(A  + (size_t)(bm + row)*256 + ks*32 + c8, &Al[ks][row][c8]);
    gload_lds16(Bw + (size_t)(bn + row)*256 + ks*32 + c8, &Bl[ks][row][c8]);
  }
  asm volatile("s_waitcnt vmcnt(0)");
  __syncthreads();

  f32x4 acc[4][4];
  #pragma unroll
  for (int m = 0; m < 4; ++m)
    #pragma unroll
    for (int n = 0; n < 4; ++n) acc[m][n] = fzero;

  #pragma unroll
  for (int ks = 0; ks < 8; ++ks) {
    bf16x8 af[4], bfr[4];
    #pragma unroll
    for (int m = 0; m < 4; ++m)
      af[m] = *(const bf16x8*)&Al[ks][wm*64 + m*16 + c][g*8];
    #pragma unroll
    for (int n = 0; n < 4; ++n)
      bfr[n] = *(const bf16x8*)&Bl[ks][wn*64 + n*16 + c][g*8];
    #pragma unroll
    for (int m = 0; m < 4; ++m)
      #pragma unroll
      for (int n = 0; n < 4; ++n)
        acc[m][n] = __builtin_amdgcn_mfma_f32_16x16x32_bf16(af[m], bfr[n], acc[m][n], 0, 0, 0);
  }

  #pragma unroll
  for (int m = 0; m < 4; ++m) {
    const int row0 = bm + wm*64 + m*16 + g*4;
    #pragma unroll
    for (int n = 0; n < 4; ++n) {
      const int col = bn + wn*64 + n*16 + c;
      if (MODE == 1) {
        const float bb = bias0[col];
        #pragma unroll
        for (int r = 0; r < 4; ++r) {
          const float vv = fmaxf(acc[m][n][r] + bb, 0.f);
          const float other = __shfl_xor(vv, 1);
          if ((c & 1) == 0) {
            const uint32_t word = (uint32_t)f2bf(vv) | ((uint32_t)f2bf(other) << 16);
            *(uint32_t*)((ushort*)Cout + (size_t)(row0 + r)*NDIM + col) = word;
          }
        }
      } else {  // MODE 3
        const int b_ = row0 >> 10, s = row0 & (SEQ - 1);
        if (col < 512) {
          const int hd = col & 255;
          const int hh = hd >> 5, d = hd & 31;
          const float bb = (col < 256) ? bias0[hd] : bias1[hd];
          ushort* dst = (ushort*)Cout + (col < 256 ? 0 : QKSTRIDE)
                      + (((size_t)(b_*NH + hh)*SEQ + s) << 5) + d;
          #pragma unroll
          for (int r = 0; r < 4; ++r) {
            const float vv = acc[m][n][r] + bb;
            const float other = __shfl_xor(vv, 1);
            if ((c & 1) == 0) {
              const uint32_t word = (uint32_t)f2bf(vv) | ((uint32_t)f2bf(other) << 16);
              *(uint32_t*)(dst + (r << 5)) = word;
            }
          }
        } else {
          // V: permuted k-slot layout. position p = g'*8 + hi*4 + rr <-> key 16*hi+4*g'+rr
          const int hd = col - 512;
          const int hh = hd >> 5, d = hd & 31;
          const float bb = bias2[hd];
          const int sg = s >> 5, a = (s & 31) >> 2;
          const int pbase = (a & 3)*8 + (a >> 2)*4;
          ushort4 w4;
          w4.x = f2bf(acc[m][n][0] + bb);
          w4.y = f2bf(acc[m][n][1] + bb);
          w4.z = f2bf(acc[m][n][2] + bb);
          w4.w = f2bf(acc[m][n][3] + bb);
          *(ushort4*)(vtb + (((size_t)((b_*NH + hh)*32 + sg)*32 + d) << 5) + pbase) = w4;
        }
      }
    }
  }
}

// ---------------- chunked-K 64x64 accumulate GEMM (N=256): C += A@B^T + bias ----------------
// KC=256 per chunk fully staged (64 KB LDS -> 2 blocks/CU), 1 barrier-pair per chunk.
// 4 waves 2x2, each 32x32 (2x2 frags). grid (4, 128) = 512 blocks.
template<int KDIM>
__global__ __launch_bounds__(256) void gemm_chunk(
    const ushort* __restrict__ A, const ushort* __restrict__ Bw,
    const float* __restrict__ bias, float* __restrict__ C)
{
  __shared__ ushort Al[8][64][32];
  __shared__ ushort Bl[8][64][32];
  const int bm = blockIdx.y * 64, bn = blockIdx.x * 64;
  const int tid = threadIdx.x, w = tid >> 6, lane = tid & 63;
  const int wm = w >> 1, wn = w & 1;
  const int g = lane >> 4, c = lane & 15;
  const f32x4 fzero = {0.f, 0.f, 0.f, 0.f};
  f32x4 acc[2][2];
  acc[0][0] = fzero; acc[0][1] = fzero; acc[1][0] = fzero; acc[1][1] = fzero;

  for (int kc = 0; kc < KDIM; kc += 256) {
    if (kc) __syncthreads();
    #pragma unroll
    for (int p = 0; p < 8; ++p) {
      const int i = p*256 + tid;             // [0,2048)
      const int ks = i >> 8, row = (i >> 2) & 63, c8 = (i & 3) * 8;
      gload_lds16(A  + (size_t)(bm + row)*KDIM + kc + ks*32 + c8, &Al[ks][row][c8]);
      gload_lds16(Bw + (size_t)(bn + row)*KDIM + kc + ks*32 + c8, &Bl[ks][row][c8]);
    }
    asm volatile("s_waitcnt vmcnt(0)");
    __syncthreads();
    #pragma unroll
    for (int ks = 0; ks < 8; ++ks) {
      bf16x8 af[2], bfr[2];
      #pragma unroll
      for (int m = 0; m < 2; ++m)
        af[m] = *(const bf16x8*)&Al[ks][wm*32 + m*16 + c][g*8];
      #pragma unroll
      for (int n = 0; n < 2; ++n)
        bfr[n] = *(const bf16x8*)&Bl[ks][wn*32 + n*16 + c][g*8];
      #pragma unroll
      for (int m = 0; m < 2; ++m)
        #pragma unroll
        for (int n = 0; n < 2; ++n)
          acc[m][n] = __builtin_amdgcn_mfma_f32_16x16x32_bf16(af[m], bfr[n], acc[m][n], 0, 0, 0);
    }
  }

  #pragma unroll
  for (int m = 0; m < 2; ++m) {
    const int row0 = bm + wm*32 + m*16 + g*4;
    #pragma unroll
    for (int n = 0; n < 2; ++n) {
      const int col = bn + wn*32 + n*16 + c;
      const float bb = bias[col];
      #pragma unroll
      for (int r = 0; r < 4; ++r)
        C[(size_t)(row0 + r)*DIM + col] += acc[m][n][r] + bb;
    }
  }
}

// ---------------- flash-decode attention: 4-way key split, in-block LDS combine ----------------
// grid 4096 x 256 threads; bijective XCD chunking; block = (b,h,q16), wave w = keys [w*256,+256).
// Softmax entirely lane-local (defer-max THR=8, deferred l-reduction, cvt_pk packing).
__global__ __launch_bounds__(256) void attn_mfma(
    const ushort* __restrict__ qh, const ushort* __restrict__ kh,
    const ushort* __restrict__ vph, const float* __restrict__ bm2l,
    ushort* __restrict__ O)
{
  const int bid = blockIdx.x;
  const int lin = ((bid & 7) << 9) + (bid >> 3);       // bijective (4096 % 8 == 0)
  const int tid = threadIdx.x, w = tid >> 6, lane = tid & 63;
  const int qw = lin & 63, h = (lin >> 6) & 7, b = lin >> 9;
  const int qb = qw << 4;
  const float scale2 = 0.17677669529663687f * 1.4426950408889634f;  // rsqrt(32)*log2e
  const int g = lane >> 4, c = lane & 15;
  const f32x4 fzero = {0.f, 0.f, 0.f, 0.f};
  const size_t bh = (size_t)(b*NH + h);

  const bf16x8 qf = *(const bf16x8*)(qh + ((bh*SEQ + qb + c) << 5) + g*8);
  const ushort* kbase = kh  + ((bh*SEQ) << 5) + g*8;   // + key*32
  const ushort* vbase = vph + ((bh*SEQ) << 5) + g*8;   // + (sg*32 + d)*32
  const float*  bmb   = bm2l + b*SEQ;

  f32x4 oacc[2]; oacc[0] = fzero; oacc[1] = fzero;
  float m_run = -1e30f, l_part = 0.f;

  bf16x8 kfA[4], kfB[4];
  bf16x8 vfA[2][2], vfB[2][2];
  f32x4 bbA[4], bbB[4];

#define LOADT(kt, kf, vf, bb)                                                  \
  {                                                                            \
    _Pragma("unroll")                                                          \
    for (int ks = 0; ks < 4; ++ks) {                                           \
      kf[ks] = *(const bf16x8*)(kbase + (((kt) + ks*16 + c) << 5));            \
      bb[ks] = *(const f32x4*)(bmb + (kt) + ks*16 + g*4);                      \
    }                                                                          \
    _Pragma("unroll")                                                          \
    for (int ds_ = 0; ds_ < 2; ++ds_)                                          \
      _Pragma("unroll")                                                        \
      for (int sg = 0; sg < 2; ++sg)                                           \
        vf[ds_][sg] = *(const bf16x8*)(vbase +                                 \
            (((((kt) >> 5) + sg)*32 + ds_*16 + c) << 5));                      \
  }

#define ATILE(kf, vf, bb)                                                      \
  {                                                                            \
    f32x4 sf[4];                                                               \
    __builtin_amdgcn_s_setprio(1);                                             \
    _Pragma("unroll")                                                          \
    for (int ks = 0; ks < 4; ++ks)                                             \
      sf[ks] = __builtin_amdgcn_mfma_f32_16x16x32_bf16(kf[ks], qf, fzero, 0, 0, 0); \
    __builtin_amdgcn_s_setprio(0);                                             \
    float p[4][4];                                                             \
    _Pragma("unroll")                                                          \
    for (int ks = 0; ks < 4; ++ks)                                             \
      _Pragma("unroll")                                                        \
      for (int r = 0; r < 4; ++r)                                              \
        p[ks][r] = fmaf(sf[ks][r], scale2, bb[ks][r]);                         \
    float mx0 = fmaxf(fmaxf(p[0][0], p[0][1]), fmaxf(p[0][2], p[0][3]));       \
    float mx1 = fmaxf(fmaxf(p[1][0], p[1][1]), fmaxf(p[1][2], p[1][3]));       \
    float mx2 = fmaxf(fmaxf(p[2][0], p[2][1]), fmaxf(p[2][2], p[2][3]));       \
    float mx3 = fmaxf(fmaxf(p[3][0], p[3][1]), fmaxf(p[3][2], p[3][3]));       \
    const float pmax = fmaxf(fmaxf(mx0, mx1), fmaxf(mx2, mx3));                \
    if (!__all(pmax <= m_run + 8.f)) {                                         \
      float tmax = pmax;                                                       \
      tmax = fmaxf(tmax, __shfl_xor(tmax, 16));                                \
      tmax = fmaxf(tmax, __shfl_xor(tmax, 32));                                \
      const float m_new = fmaxf(m_run, tmax);                                  \
      const float sc = exp2_n(m_run - m_new);                                  \
      m_run = m_new;                                                           \
      l_part *= sc;                                                            \
      oacc[0] *= sc; oacc[1] *= sc;                                            \
    }                                                                          \
    float e[4][4];                                                             \
    _Pragma("unroll")                                                          \
    for (int ks = 0; ks < 4; ++ks)                                             \
      _Pragma("unroll")                                                        \
      for (int r = 0; r < 4; ++r)                                              \
        e[ks][r] = exp2_n(p[ks][r] - m_run);                                   \
    float s0 = 0.f, s1 = 0.f, s2 = 0.f, s3 = 0.f;                              \
    _Pragma("unroll")                                                          \
    for (int r = 0; r < 4; ++r) {                                              \
      s0 += e[0][r]; s1 += e[1][r]; s2 += e[2][r]; s3 += e[3][r];              \
    }                                                                          \
    l_part += (s0 + s1) + (s2 + s3);                                           \
    union { bf16x8 v; uint32_t u[4]; } pb0, pb1;                               \
    pb0.u[0] = cvtpk(e[0][0], e[0][1]); pb0.u[1] = cvtpk(e[0][2], e[0][3]);    \
    pb0.u[2] = cvtpk(e[1][0], e[1][1]); pb0.u[3] = cvtpk(e[1][2], e[1][3]);    \
    pb1.u[0] = cvtpk(e[2][0], e[2][1]); pb1.u[1] = cvtpk(e[2][2], e[2][3]);    \
    pb1.u[2] = cvtpk(e[3][0], e[3][1]); pb1.u[3] = cvtpk(e[3][2], e[3][3]);    \
    __builtin_amdgcn_s_setprio(1);                                             \
    oacc[0] = __builtin_amdgcn_mfma_f32_16x16x32_bf16(vf[0][0], pb0.v, oacc[0], 0, 0, 0); \
    oacc[1] = __builtin_amdgcn_mfma_f32_16x16x32_bf16(vf[1][0], pb0.v, oacc[1], 0, 0, 0); \
    oacc[0] = __builtin_amdgcn_mfma_f32_16x16x32_bf16(vf[0][1], pb1.v, oacc[0], 0, 0, 0); \
    oacc[1] = __builtin_amdgcn_mfma_f32_16x16x32_bf16(vf[1][1], pb1.v, oacc[1], 0, 0, 0); \
    __builtin_amdgcn_s_setprio(0);                                             \
  }

  const int kt0 = w << 8;
  LOADT(kt0, kfA, vfA, bbA);
  LOADT(kt0 + 64, kfB, vfB, bbB);
  ATILE(kfA, vfA, bbA);
  LOADT(kt0 + 128, kfA, vfA, bbA);
  ATILE(kfB, vfB, bbB);
  LOADT(kt0 + 192, kfB, vfB, bbB);
  ATILE(kfA, vfA, bbA);
  ATILE(kfB, vfB, bbB);
#undef LOADT
#undef ATILE

  // ---- in-block combine of the 4 key-quarter partials ----
  __shared__ float Lo[4][64][9];
  __shared__ float Lm[4];
  #pragma unroll
  for (int i = 0; i < 4; ++i) {
    Lo[w][lane][i]     = oacc[0][i];
    Lo[w][lane][4 + i] = oacc[1][i];
  }
  Lo[w][lane][8] = l_part;
  if (lane == 0) Lm[w] = m_run;
  __syncthreads();
  if (w == 0) {
    const float m0 = Lm[0], m1 = Lm[1], m2 = Lm[2], m3 = Lm[3];
    const float nm = fmaxf(fmaxf(m0, m1), fmaxf(m2, m3));
    const float sws[4] = { exp2_n(m0 - nm), exp2_n(m1 - nm),
                           exp2_n(m2 - nm), exp2_n(m3 - nm) };
    float o[8] = {0.f,0.f,0.f,0.f,0.f,0.f,0.f,0.f};
    float l = 0.f;
    #pragma unroll
    for (int ww = 0; ww < 4; ++ww) {
      const float sw = sws[ww];
      l += Lo[ww][lane][8] * sw;
      #pragma unroll
      for (int i = 0; i < 8; ++i) o[i] += Lo[ww][lane][i] * sw;
    }
    l += __shfl_xor(l, 16);
    l += __shfl_xor(l, 32);
    const float inv = 1.f / l;
    ushort* orow = O + (size_t)(b*SEQ + qb + c)*DIM + h*32 + g*4;
    const uint32_t w0 = (uint32_t)f2bf(o[0]*inv) | ((uint32_t)f2bf(o[1]*inv) << 16);
    const uint32_t w1 = (uint32_t)f2bf(o[2]*inv) | ((uint32_t)f2bf(o[3]*inv) << 16);
    const uint32_t w2 = (uint32_t)f2bf(o[4]*inv) | ((uint32_t)f2bf(o[5]*inv) << 16);
    const uint32_t w3 = (uint32_t)f2bf(o[6]*inv) | ((uint32_t)f2bf(o[7]*inv) << 16);
    *(uint32_t*)(orow)      = w0;
    *(uint32_t*)(orow + 2)  = w1;
    *(uint32_t*)(orow + 16) = w2;
    *(uint32_t*)(orow + 18) = w3;
  }
}

// ---------------- final LN (row 0 per batch) + classifier ----------------
__global__ __launch_bounds__(256) void cls_kernel(
    const float* __restrict__ x, const float* __restrict__ gf,
    const float* __restrict__ bf, const float* __restrict__ Wc,
    const float* __restrict__ bc, float* __restrict__ out)
{
  const int b = blockIdx.x;
  const int tid = threadIdx.x;
  const int wave = tid >> 6, lane = tid & 63;
  const float* xr = x + (size_t)b * SEQ * DIM;
  const float v = xr[tid];
  __shared__ float redm[4], redv[4], redc[4][4];
  float s = v;
  #pragma unroll
  for (int o = 32; o >= 1; o >>= 1) s += __shfl_xor(s, o);
  if (lane == 0) redm[wave] = s;
  __syncthreads();
  const float mean = (redm[0]+redm[1]+redm[2]+redm[3]) * (1.f/256.f);
  const float dv = v - mean;
  float q = dv * dv;
  #pragma unroll
  for (int o = 32; o >= 1; o >>= 1) q += __shfl_xor(q, o);
  if (lane == 0) redv[wave] = q;
  __syncthreads();
  const float var = (redv[0]+redv[1]+redv[2]+redv[3]) * (1.f/256.f);
  const float rs = rsqrtf(var + 1e-5f);
  const float yn = dv*rs*gf[tid] + bf[tid];
  float pc[4];
  #pragma unroll
  for (int cc = 0; cc < 4; ++cc) pc[cc] = yn * Wc[tid*4 + cc];
  #pragma unroll
  for (int cc = 0; cc < 4; ++cc) {
    #pragma unroll
    for (int o = 32; o >= 1; o >>= 1) pc[cc] += __shfl_xor(pc[cc], o);
  }
  if (lane == 0) {
    #pragma unroll
    for (int cc = 0; cc < 4; ++cc) redc[wave][cc] = pc[cc];
  }
  __syncthreads();
  if (tid < 4)
    out[b*4 + tid] = redc[0][tid] + redc[1][tid] + redc[2][tid] + redc[3][tid] + bc[tid];
}

extern "C" void kernel_launch(void* const* d_in, const int* in_sizes, int n_in,
                              void* d_out, int out_size, void* d_ws, size_t ws_size,
                              hipStream_t stream)
{
  const int*   ids    = (const int*)d_in[0];
  const int*   ngrams = (const int*)d_in[1];
  const float* tfidf  = (const float*)d_in[2];
  const float* emb    = (const float*)d_in[3];
  const float* pos    = (const float*)d_in[4];
  const float* bucket = (const float*)d_in[5];
  const float* Wq = (const float*)d_in[6];  const float* bq = (const float*)d_in[7];
  const float* Wk = (const float*)d_in[8];  const float* bk = (const float*)d_in[9];
  const float* Wv = (const float*)d_in[10]; const float* bv = (const float*)d_in[11];
  const float* Wo = (const float*)d_in[12]; const float* bo = (const float*)d_in[13];
  const float* g1 = (const float*)d_in[14]; const float* be1= (const float*)d_in[15];
  const float* g2 = (const float*)d_in[16]; const float* be2= (const float*)d_in[17];
  const float* W1 = (const float*)d_in[18]; const float* b1 = (const float*)d_in[19];
  const float* W2 = (const float*)d_in[20]; const float* b2 = (const float*)d_in[21];
  const float* alpha = (const float*)d_in[22];
  const float* gf = (const float*)d_in[23]; const float* bf = (const float*)d_in[24];
  const float* Wc = (const float*)d_in[25]; const float* bc = (const float*)d_in[26];

  uint8_t* base = (uint8_t*)d_ws;
  float*  x      = (float*)  base;                  //  8,388,608
  ushort* x2b    = (ushort*)(base + 8388608);       //  4,194,304
  ushort* qkh    = (ushort*)(base + 12582912);      //  8,388,608 (Q head-major, K at +QKSTRIDE)
  ushort* vtb    = (ushort*)(base + 20971520);      //  4,194,304 (V permuted)
  ushort* attb   = (ushort*)(base + 25165824);      //  4,194,304
  ushort* midb   = (ushort*)(base + 29360128);      // 16,777,216
  float*  bm2    = (float*) (base + 46137344);      //     65,536 (2 layers)
  ushort* WqkvT  = (ushort*)(base + 46202880);      //    786,432
  ushort* WoT    = (ushort*)(base + 46989312);      //    262,144
  ushort* W1T    = (ushort*)(base + 47251456);      //  1,048,576
  ushort* W2T    = (ushort*)(base + 48300032);      //  1,048,576  -> 49,348,608 total

  TDescs td;
  for (int l = 0; l < NL; ++l) {
    td.d[6*l+0] = { Wq + (size_t)l*DIM*DIM, WqkvT + (size_t)l*768*DIM +   0*DIM, DIM, DIM };
    td.d[6*l+1] = { Wk + (size_t)l*DIM*DIM, WqkvT + (size_t)l*768*DIM + 256*DIM, DIM, DIM };
    td.d[6*l+2] = { Wv + (size_t)l*DIM*DIM, WqkvT + (size_t)l*768*DIM + 512*DIM, DIM, DIM };
    td.d[6*l+3] = { Wo + (size_t)l*DIM*DIM, WoT  + (size_t)l*DIM*DIM,  DIM, DIM };
    td.d[6*l+4] = { W1 + (size_t)l*DIM*FFD, W1T  + (size_t)l*FFD*DIM,  DIM, FFD };
    td.d[6*l+5] = { W2 + (size_t)l*FFD*DIM, W2T  + (size_t)l*DIM*FFD,  FFD, DIM };
  }
  transpose_conv<<<dim3(32, 32, 12), 256, 0, stream>>>(td);

  embed_ln_kernel<<<TOK, 256, 0, stream>>>(
      ids, ngrams, tfidf, emb, pos, bucket, alpha, g1, be1, x, x2b, bm2);

  const dim3 gqkv(6, TOK/128), gff1(8, TOK/128), gacc(4, TOK/64);
  for (int l = 0; l < NL; ++l) {
    if (l > 0)
      ln_bf16<<<TOK/4, 256, 0, stream>>>(x, g1 + l*DIM, be1 + l*DIM, x2b);
    gemm_fullk<768, 3><<<gqkv, 256, 0, stream>>>(
        x2b, WqkvT + (size_t)l*768*DIM, bq + l*DIM, bk + l*DIM, bv + l*DIM, qkh, vtb);
    attn_mfma<<<4096, 256, 0, stream>>>(qkh, qkh + QKSTRIDE, vtb, bm2 + l*TOK, attb);
    gemm_chunk<256><<<gacc, 256, 0, stream>>>(
        attb, WoT + (size_t)l*DIM*DIM, bo + l*DIM, x);
    ln_bf16<<<TOK/4, 256, 0, stream>>>(x, g2 + l*DIM, be2 + l*DIM, x2b);
    gemm_fullk<1024, 1><<<gff1, 256, 0, stream>>>(
        x2b, W1T + (size_t)l*FFD*DIM, b1 + l*FFD, nullptr, nullptr, midb, nullptr);
    gemm_chunk<1024><<<gacc, 256, 0, stream>>>(
        midb, W2T + (size_t)l*DIM*FFD, b2 + l*DIM, x);
  }
  cls_kernel<<<8, 256, 0, stream>>>(x, gf, bf, Wc, bc, (float*)d_out);
}

// Round 10
// 203.058 us; speedup vs baseline: 1.2526x; 1.2526x over previous
//
#include <hip/hip_runtime.h>
#include <hip/hip_bf16.h>
#include <math.h>

#define TOK 8192       // B*S
#define DIM 256
#define SEQ 1024
#define NH 8
#define FFD 1024
#define NL 2
#define VOCAB 32000
#define QKSTRIDE 2097152   // elems between Q and K head-major blocks

typedef short bf16x8 __attribute__((ext_vector_type(8)));
typedef float f32x4 __attribute__((ext_vector_type(4)));

__device__ __forceinline__ ushort f2bf(float f) {
  union { float f; uint32_t u; } v; v.f = f;
  uint32_t r = v.u + 0x7FFFu + ((v.u >> 16) & 1u);
  return (ushort)(r >> 16);
}

__device__ __forceinline__ float exp2_n(float x) {
  float r; asm("v_exp_f32 %0, %1" : "=v"(r) : "v"(x)); return r;
}

__device__ __forceinline__ uint32_t cvtpk(float lo, float hi) {
  uint32_t r; asm("v_cvt_pk_bf16_f32 %0, %1, %2" : "=v"(r) : "v"(lo), "v"(hi));
  return r;
}

__device__ __forceinline__ void gload_lds16(const ushort* gp, ushort* lp) {
  __builtin_amdgcn_global_load_lds(
      (const __attribute__((address_space(1))) void*)gp,
      (__attribute__((address_space(3))) void*)lp, 16, 0, 0);
}

// ---------------- embedding + ngram + tfidf bias + fused layer-0 LN ----------------
__global__ __launch_bounds__(256) void embed_ln_kernel(
    const int* __restrict__ ids, const int* __restrict__ ngram_ids,
    const float* __restrict__ tfidf, const float* __restrict__ emb,
    const float* __restrict__ pos, const float* __restrict__ bucket,
    const float* __restrict__ alpha, const float* __restrict__ g1,
    const float* __restrict__ be1,
    float* __restrict__ x, ushort* __restrict__ x2b, float* __restrict__ bm2)
{
  __shared__ int ngs[12];
  __shared__ float red[2][4];
  const int t = blockIdx.x;
  const int id = ids[t];
  int idc = id; if (idc < 0) idc = 0; if (idc > VOCAB-1) idc = VOCAB-1;
  if (threadIdx.x < 12) ngs[threadIdx.x] = ngram_ids[idc*12 + threadIdx.x];
  if (threadIdx.x == 0) {
    const float tf = tfidf[idc];
    const bool msk = (id == 0);
    const float l2e = 1.4426950408889634f;
    bm2[t]       = msk ? -1e30f : tf * alpha[0] * l2e;
    bm2[TOK + t] = msk ? -1e30f : tf * alpha[1] * l2e;
  }
  __syncthreads();
  const int d = threadIdx.x;
  const int s = t & (SEQ - 1);
  float v = emb[(size_t)id*DIM + d] + pos[s*DIM + d];
  float sum = 0.f; int cnt = 0;
  #pragma unroll
  for (int g = 0; g < 12; ++g) {
    const int ng = ngs[g];
    if (ng != 0) { sum += bucket[(size_t)ng*DIM + d]; cnt++; }
  }
  v += sum / fmaxf((float)cnt, 1.0f);
  x[(size_t)t*DIM + d] = v;
  // fused LN (layer 0, ln1)
  const int wave = d >> 6, lane = d & 63;
  float sm = v;
  #pragma unroll
  for (int o = 32; o >= 1; o >>= 1) sm += __shfl_xor(sm, o);
  if (lane == 0) red[0][wave] = sm;
  __syncthreads();
  const float mean = (red[0][0]+red[0][1]+red[0][2]+red[0][3]) * (1.f/256.f);
  const float dv = v - mean;
  float q = dv * dv;
  #pragma unroll
  for (int o = 32; o >= 1; o >>= 1) q += __shfl_xor(q, o);
  if (lane == 0) red[1][wave] = q;
  __syncthreads();
  const float var = (red[1][0]+red[1][1]+red[1][2]+red[1][3]) * (1.f/256.f);
  const float rs = rsqrtf(var + 1e-5f);
  x2b[(size_t)t*DIM + d] = f2bf(dv*rs*g1[d] + be1[d]);
}

// ---------------- layernorm -> bf16 ----------------
__global__ __launch_bounds__(256) void ln_bf16(
    const float* __restrict__ x, const float* __restrict__ g,
    const float* __restrict__ b, ushort* __restrict__ y)
{
  const int wave = threadIdx.x >> 6, lane = threadIdx.x & 63;
  const int row = blockIdx.x * 4 + wave;
  const float* xr = x + (size_t)row * DIM;
  float4 v = *reinterpret_cast<const float4*>(xr + lane*4);
  float s = v.x + v.y + v.z + v.w;
  #pragma unroll
  for (int o = 32; o >= 1; o >>= 1) s += __shfl_xor(s, o);
  const float mean = s * (1.f/256.f);
  const float dx0 = v.x-mean, dx1 = v.y-mean, dx2 = v.z-mean, dx3 = v.w-mean;
  float q = dx0*dx0 + dx1*dx1 + dx2*dx2 + dx3*dx3;
  #pragma unroll
  for (int o = 32; o >= 1; o >>= 1) q += __shfl_xor(q, o);
  const float rs = rsqrtf(q * (1.f/256.f) + 1e-5f);
  float4 gv = *reinterpret_cast<const float4*>(g + lane*4);
  float4 bv = *reinterpret_cast<const float4*>(b + lane*4);
  ushort4 o4;
  o4.x = f2bf(dx0*rs*gv.x + bv.x);
  o4.y = f2bf(dx1*rs*gv.y + bv.y);
  o4.z = f2bf(dx2*rs*gv.z + bv.z);
  o4.w = f2bf(dx3*rs*gv.w + bv.w);
  *reinterpret_cast<ushort4*>(y + (size_t)row*DIM + lane*4) = o4;
}

// ---------------- weight transpose + bf16: f32 [K][N] -> bf16 [N][K] ----------------
struct TDesc { const float* src; ushort* dst; int K; int N; };
struct TDescs { TDesc d[12]; };

__global__ __launch_bounds__(256) void transpose_conv(TDescs descs)
{
  const TDesc t = descs.d[blockIdx.z];
  const int k0 = blockIdx.x * 32, n0 = blockIdx.y * 32;
  if (k0 >= t.K || n0 >= t.N) return;
  __shared__ float tile[32][33];
  const int r = threadIdx.x >> 5, cc = threadIdx.x & 31;
  #pragma unroll
  for (int i = 0; i < 4; ++i)
    tile[r + i*8][cc] = t.src[(size_t)(k0 + r + i*8)*t.N + n0 + cc];
  __syncthreads();
  #pragma unroll
  for (int i = 0; i < 4; ++i)
    t.dst[(size_t)(n0 + r + i*8)*t.K + k0 + cc] = f2bf(tile[cc][r + i*8]);
}

// ---------------- bf16 MFMA GEMM: C[M,N] = A[M,K] @ B^T  (B as [N][K]) ----------------
// BM=64, BN=128, BK=32; 4 waves, wave w owns cols [w*32, w*32+32); frags 4x2.  (R6-proven)
// MODE 1: relu + bf16 out;
// MODE 3: qkv -> Q,K head-major [b][h][s][32] (Cout, +QKSTRIDE for K);
//         V permuted into vtb[b][h][sg][d][32 perm keys].
template<int KDIM, int NDIM, int MODE>
__global__ __launch_bounds__(256) void gemm_mfma(
    const ushort* __restrict__ A, const ushort* __restrict__ Bw,
    const float* __restrict__ bias0, const float* __restrict__ bias1,
    const float* __restrict__ bias2, void* __restrict__ Cout,
    ushort* __restrict__ vtb)
{
  __shared__ ushort Al[2][64*32];
  __shared__ ushort Bl[2][128*32];
  const int bm = blockIdx.y * 64, bn = blockIdx.x * 128;
  const int tid = threadIdx.x, w = tid >> 6, lane = tid & 63;
  const int g = lane >> 4, c = lane & 15;
  const int lrow = lane >> 2, lc8 = (lane & 3) * 8;
  const f32x4 fzero = {0.f, 0.f, 0.f, 0.f};
  f32x4 acc[4][2];
  #pragma unroll
  for (int m = 0; m < 4; ++m) { acc[m][0] = fzero; acc[m][1] = fzero; }

#define STAGE(buf, k0)                                                         \
  {                                                                            \
    _Pragma("unroll")                                                          \
    for (int ch = w; ch < 12; ch += 4) {                                       \
      if (ch < 4)                                                              \
        gload_lds16(A + (size_t)(bm + ch*16 + lrow)*KDIM + (k0) + lc8,         \
                    &Al[buf][ch*512]);                                         \
      else                                                                     \
        gload_lds16(Bw + (size_t)(bn + (ch-4)*16 + lrow)*KDIM + (k0) + lc8,    \
                    &Bl[buf][(ch-4)*512]);                                     \
    }                                                                          \
  }

  STAGE(0, 0);
  asm volatile("s_waitcnt vmcnt(0)");
  __syncthreads();
  int buf = 0;
  for (int k0 = 0; k0 < KDIM; k0 += 32) {
    if (k0 + 32 < KDIM) STAGE(buf^1, k0 + 32);
    bf16x8 af[4], bfr[2];
    #pragma unroll
    for (int m = 0; m < 4; ++m)
      af[m] = *(const bf16x8*)&Al[buf][(m*16 + c)*32 + g*8];
    #pragma unroll
    for (int n = 0; n < 2; ++n)
      bfr[n] = *(const bf16x8*)&Bl[buf][(w*32 + n*16 + c)*32 + g*8];
    #pragma unroll
    for (int m = 0; m < 4; ++m)
      #pragma unroll
      for (int n = 0; n < 2; ++n)
        acc[m][n] = __builtin_amdgcn_mfma_f32_16x16x32_bf16(af[m], bfr[n], acc[m][n], 0, 0, 0);
    asm volatile("s_waitcnt vmcnt(0)");
    __syncthreads();
    buf ^= 1;
  }
#undef STAGE

  #pragma unroll
  for (int m = 0; m < 4; ++m) {
    const int row0 = bm + m*16 + g*4;
    #pragma unroll
    for (int n = 0; n < 2; ++n) {
      const int col = bn + w*32 + n*16 + c;
      if (MODE == 1) {
        const float bb = bias0[col];
        #pragma unroll
        for (int r = 0; r < 4; ++r) {
          const float vv = fmaxf(acc[m][n][r] + bb, 0.f);
          const float other = __shfl_xor(vv, 1);
          if ((c & 1) == 0) {
            const uint32_t word = (uint32_t)f2bf(vv) | ((uint32_t)f2bf(other) << 16);
            *(uint32_t*)((ushort*)Cout + (size_t)(row0 + r)*NDIM + col) = word;
          }
        }
      } else {  // MODE 3
        const int b_ = row0 >> 10, s = row0 & (SEQ - 1);
        if (col < 512) {
          const int hd = col & 255;
          const int hh = hd >> 5, d = hd & 31;
          const float bb = (col < 256) ? bias0[hd] : bias1[hd];
          ushort* dst = (ushort*)Cout + (col < 256 ? 0 : QKSTRIDE)
                      + (((size_t)(b_*NH + hh)*SEQ + s) << 5) + d;
          #pragma unroll
          for (int r = 0; r < 4; ++r) {
            const float vv = acc[m][n][r] + bb;
            const float other = __shfl_xor(vv, 1);
            if ((c & 1) == 0) {
              const uint32_t word = (uint32_t)f2bf(vv) | ((uint32_t)f2bf(other) << 16);
              *(uint32_t*)(dst + (r << 5)) = word;
            }
          }
        } else {
          // V: permuted k-slot layout. position p = g'*8 + hi*4 + rr <-> key 16*hi+4*g'+rr
          const int hd = col - 512;
          const int hh = hd >> 5, d = hd & 31;
          const float bb = bias2[hd];
          const int sg = s >> 5, a = (s & 31) >> 2;
          const int pbase = (a & 3)*8 + (a >> 2)*4;
          ushort4 w4;
          w4.x = f2bf(acc[m][n][0] + bb);
          w4.y = f2bf(acc[m][n][1] + bb);
          w4.z = f2bf(acc[m][n][2] + bb);
          w4.w = f2bf(acc[m][n][3] + bb);
          *(ushort4*)(vtb + (((size_t)((b_*NH + hh)*32 + sg)*32 + d) << 5) + pbase) = w4;
        }
      }
    }
  }
}

// ---------------- 64x64-tile accumulate GEMM (N=256): C[M,256] += A@B^T + bias (R6-proven) ----------------
template<int KDIM>
__global__ __launch_bounds__(256) void gemm64_acc(
    const ushort* __restrict__ A, const ushort* __restrict__ Bw,
    const float* __restrict__ bias, float* __restrict__ C)
{
  __shared__ ushort Al[2][64*32];
  __shared__ ushort Bl[2][64*32];
  const int bm = blockIdx.y * 64, bn = blockIdx.x * 64;
  const int tid = threadIdx.x, w = tid >> 6, lane = tid & 63;
  const int wm = w >> 1, wn = w & 1;
  const int g = lane >> 4, c = lane & 15;
  const int lrow = tid >> 2, lc8 = (tid & 3) * 8;
  const f32x4 fzero = {0.f, 0.f, 0.f, 0.f};
  f32x4 acc[2][2];
  acc[0][0] = fzero; acc[0][1] = fzero; acc[1][0] = fzero; acc[1][1] = fzero;

#define STAGE64(buf, k0)                                                       \
  {                                                                            \
    gload_lds16(A  + (size_t)(bm + lrow)*KDIM + (k0) + lc8,                    \
                &Al[buf][lrow*32 + lc8]);                                      \
    gload_lds16(Bw + (size_t)(bn + lrow)*KDIM + (k0) + lc8,                    \
                &Bl[buf][lrow*32 + lc8]);                                      \
  }

  STAGE64(0, 0);
  asm volatile("s_waitcnt vmcnt(0)");
  __syncthreads();
  int buf = 0;
  for (int k0 = 0; k0 < KDIM; k0 += 32) {
    if (k0 + 32 < KDIM) STAGE64(buf^1, k0 + 32);
    bf16x8 af[2], bfr[2];
    #pragma unroll
    for (int m = 0; m < 2; ++m)
      af[m] = *(const bf16x8*)&Al[buf][(wm*32 + m*16 + c)*32 + g*8];
    #pragma unroll
    for (int n = 0; n < 2; ++n)
      bfr[n] = *(const bf16x8*)&Bl[buf][(wn*32 + n*16 + c)*32 + g*8];
    #pragma unroll
    for (int m = 0; m < 2; ++m)
      #pragma unroll
      for (int n = 0; n < 2; ++n)
        acc[m][n] = __builtin_amdgcn_mfma_f32_16x16x32_bf16(af[m], bfr[n], acc[m][n], 0, 0, 0);
    asm volatile("s_waitcnt vmcnt(0)");
    __syncthreads();
    buf ^= 1;
  }
#undef STAGE64

  #pragma unroll
  for (int m = 0; m < 2; ++m) {
    const int row0 = bm + wm*32 + m*16 + g*4;
    #pragma unroll
    for (int n = 0; n < 2; ++n) {
      const int col = bn + wn*32 + n*16 + c;
      const float bb = bias[col];
      #pragma unroll
      for (int r = 0; r < 4; ++r)
        C[(size_t)(row0 + r)*DIM + col] += acc[m][n][r] + bb;
    }
  }
}

// ---------------- flash attention: 32 q-rows/block, 4-way key split, max-free softmax ----------------
// grid 2048 x 256 threads; bijective XCD chunking; block = (b,h,q32), wave w = keys [w*256,+256).
// Each wave: 2 Q frags (rows qb+c, qb+16+c). No max tracking (scores bounded ±~10 in base-2:
// exp2 directly; masked keys bias=-1e30 -> exp2 -> 0). Combine = pure sum via LDS.
__global__ __launch_bounds__(256) void attn_mfma(
    const ushort* __restrict__ qh, const ushort* __restrict__ kh,
    const ushort* __restrict__ vph, const float* __restrict__ bm2l,
    ushort* __restrict__ O)
{
  const int bid = blockIdx.x;
  const int lin = ((bid & 7) << 8) + (bid >> 3);       // bijective (2048 % 8 == 0)
  const int tid = threadIdx.x, w = tid >> 6, lane = tid & 63;
  const int qw = lin & 31, h = (lin >> 5) & 7, b = lin >> 8;
  const int qb = qw << 5;
  const float scale2 = 0.17677669529663687f * 1.4426950408889634f;  // rsqrt(32)*log2e
  const int g = lane >> 4, c = lane & 15;
  const f32x4 fzero = {0.f, 0.f, 0.f, 0.f};
  const size_t bh = (size_t)(b*NH + h);

  const bf16x8 qf0 = *(const bf16x8*)(qh + ((bh*SEQ + qb + c)      << 5) + g*8);
  const bf16x8 qf1 = *(const bf16x8*)(qh + ((bh*SEQ + qb + 16 + c) << 5) + g*8);
  const ushort* kbase = kh  + ((bh*SEQ) << 5) + g*8;   // + key*32
  const ushort* vbase = vph + ((bh*SEQ) << 5) + g*8;   // + (sg*32 + d)*32
  const float*  bmb   = bm2l + b*SEQ;

  f32x4 oacc[2][2];                                    // [q][ds]
  oacc[0][0] = fzero; oacc[0][1] = fzero; oacc[1][0] = fzero; oacc[1][1] = fzero;
  float l0 = 0.f, l1 = 0.f;

  bf16x8 kfA[4], kfB[4];
  bf16x8 vfA[2][2], vfB[2][2];
  f32x4 bbA[4], bbB[4];

#define LOADT(kt, kf, vf, bb)                                                  \
  {                                                                            \
    _Pragma("unroll")                                                          \
    for (int ks = 0; ks < 4; ++ks) {                                           \
      kf[ks] = *(const bf16x8*)(kbase + (((kt) + ks*16 + c) << 5));            \
      bb[ks] = *(const f32x4*)(bmb + (kt) + ks*16 + g*4);                      \
    }                                                                          \
    _Pragma("unroll")                                                          \
    for (int ds_ = 0; ds_ < 2; ++ds_)                                          \
      _Pragma("unroll")                                                        \
      for (int sg = 0; sg < 2; ++sg)                                           \
        vf[ds_][sg] = *(const bf16x8*)(vbase +                                 \
            (((((kt) >> 5) + sg)*32 + ds_*16 + c) << 5));                      \
  }

#define ATILE(kf, vf, bb)                                                      \
  {                                                                            \
    f32x4 sf0[4], sf1[4];                                                      \
    __builtin_amdgcn_s_setprio(1);                                             \
    _Pragma("unroll")                                                          \
    for (int ks = 0; ks < 4; ++ks)                                             \
      sf0[ks] = __builtin_amdgcn_mfma_f32_16x16x32_bf16(kf[ks], qf0, fzero, 0, 0, 0); \
    _Pragma("unroll")                                                          \
    for (int ks = 0; ks < 4; ++ks)                                             \
      sf1[ks] = __builtin_amdgcn_mfma_f32_16x16x32_bf16(kf[ks], qf1, fzero, 0, 0, 0); \
    __builtin_amdgcn_s_setprio(0);                                             \
    float e0[4][4], e1[4][4];                                                  \
    _Pragma("unroll")                                                          \
    for (int ks = 0; ks < 4; ++ks)                                             \
      _Pragma("unroll")                                                        \
      for (int r = 0; r < 4; ++r) {                                            \
        e0[ks][r] = exp2_n(fmaf(sf0[ks][r], scale2, bb[ks][r]));               \
        e1[ks][r] = exp2_n(fmaf(sf1[ks][r], scale2, bb[ks][r]));               \
      }                                                                        \
    float a0 = 0.f, a1 = 0.f, a2 = 0.f, a3 = 0.f;                              \
    _Pragma("unroll")                                                          \
    for (int r = 0; r < 4; ++r) {                                              \
      a0 += e0[0][r] + e0[1][r]; a1 += e0[2][r] + e0[3][r];                    \
      a2 += e1[0][r] + e1[1][r]; a3 += e1[2][r] + e1[3][r];                    \
    }                                                                          \
    l0 += a0 + a1; l1 += a2 + a3;                                              \
    union { bf16x8 v; uint32_t u[4]; } p00, p01, p10, p11;                     \
    p00.u[0] = cvtpk(e0[0][0], e0[0][1]); p00.u[1] = cvtpk(e0[0][2], e0[0][3]);\
    p00.u[2] = cvtpk(e0[1][0], e0[1][1]); p00.u[3] = cvtpk(e0[1][2], e0[1][3]);\
    p01.u[0] = cvtpk(e0[2][0], e0[2][1]); p01.u[1] = cvtpk(e0[2][2], e0[2][3]);\
    p01.u[2] = cvtpk(e0[3][0], e0[3][1]); p01.u[3] = cvtpk(e0[3][2], e0[3][3]);\
    p10.u[0] = cvtpk(e1[0][0], e1[0][1]); p10.u[1] = cvtpk(e1[0][2], e1[0][3]);\
    p10.u[2] = cvtpk(e1[1][0], e1[1][1]); p10.u[3] = cvtpk(e1[1][2], e1[1][3]);\
    p11.u[0] = cvtpk(e1[2][0], e1[2][1]); p11.u[1] = cvtpk(e1[2][2], e1[2][3]);\
    p11.u[2] = cvtpk(e1[3][0], e1[3][1]); p11.u[3] = cvtpk(e1[3][2], e1[3][3]);\
    __builtin_amdgcn_s_setprio(1);                                             \
    oacc[0][0] = __builtin_amdgcn_mfma_f32_16x16x32_bf16(vf[0][0], p00.v, oacc[0][0], 0, 0, 0); \
    oacc[0][1] = __builtin_amdgcn_mfma_f32_16x16x32_bf16(vf[1][0], p00.v, oacc[0][1], 0, 0, 0); \
    oacc[1][0] = __builtin_amdgcn_mfma_f32_16x16x32_bf16(vf[0][0], p10.v, oacc[1][0], 0, 0, 0); \
    oacc[1][1] = __builtin_amdgcn_mfma_f32_16x16x32_bf16(vf[1][0], p10.v, oacc[1][1], 0, 0, 0); \
    oacc[0][0] = __builtin_amdgcn_mfma_f32_16x16x32_bf16(vf[0][1], p01.v, oacc[0][0], 0, 0, 0); \
    oacc[0][1] = __builtin_amdgcn_mfma_f32_16x16x32_bf16(vf[1][1], p01.v, oacc[0][1], 0, 0, 0); \
    oacc[1][0] = __builtin_amdgcn_mfma_f32_16x16x32_bf16(vf[0][1], p11.v, oacc[1][0], 0, 0, 0); \
    oacc[1][1] = __builtin_amdgcn_mfma_f32_16x16x32_bf16(vf[1][1], p11.v, oacc[1][1], 0, 0, 0); \
    __builtin_amdgcn_s_setprio(0);                                             \
  }

  const int kt0 = w << 8;
  LOADT(kt0, kfA, vfA, bbA);
  LOADT(kt0 + 64, kfB, vfB, bbB);
  ATILE(kfA, vfA, bbA);
  LOADT(kt0 + 128, kfA, vfA, bbA);
  ATILE(kfB, vfB, bbB);
  LOADT(kt0 + 192, kfB, vfB, bbB);
  ATILE(kfA, vfA, bbA);
  ATILE(kfB, vfB, bbB);
#undef LOADT
#undef ATILE

  // ---- in-block SUM combine of the 4 key-quarter partials (no max -> no rescale) ----
  __shared__ float Lo[4][64][19];   // stride 19 floats: odd -> 2-way max bank aliasing
  #pragma unroll
  for (int q = 0; q < 2; ++q)
    #pragma unroll
    for (int ds_ = 0; ds_ < 2; ++ds_)
      #pragma unroll
      for (int i = 0; i < 4; ++i)
        Lo[w][lane][q*8 + ds_*4 + i] = oacc[q][ds_][i];
  Lo[w][lane][16] = l0;
  Lo[w][lane][17] = l1;
  __syncthreads();
  if (w < 2) {
    const int q = w;
    float o[8] = {0.f,0.f,0.f,0.f,0.f,0.f,0.f,0.f};
    float ls = 0.f;
    #pragma unroll
    for (int ww = 0; ww < 4; ++ww) {
      ls += Lo[ww][lane][16 + q];
      #pragma unroll
      for (int i = 0; i < 8; ++i) o[i] += Lo[ww][lane][q*8 + i];
    }
    ls += __shfl_xor(ls, 16);
    ls += __shfl_xor(ls, 32);
    const float inv = 1.f / ls;
    ushort* orow = O + (size_t)(b*SEQ + qb + q*16 + c)*DIM + h*32 + g*4;
    const uint32_t w0 = (uint32_t)f2bf(o[0]*inv) | ((uint32_t)f2bf(o[1]*inv) << 16);
    const uint32_t w1 = (uint32_t)f2bf(o[2]*inv) | ((uint32_t)f2bf(o[3]*inv) << 16);
    const uint32_t w2 = (uint32_t)f2bf(o[4]*inv) | ((uint32_t)f2bf(o[5]*inv) << 16);
    const uint32_t w3 = (uint32_t)f2bf(o[6]*inv) | ((uint32_t)f2bf(o[7]*inv) << 16);
    *(uint32_t*)(orow)      = w0;
    *(uint32_t*)(orow + 2)  = w1;
    *(uint32_t*)(orow + 16) = w2;
    *(uint32_t*)(orow + 18) = w3;
  }
}

// ---------------- final LN (row 0 per batch) + classifier ----------------
__global__ __launch_bounds__(256) void cls_kernel(
    const float* __restrict__ x, const float* __restrict__ gf,
    const float* __restrict__ bf, const float* __restrict__ Wc,
    const float* __restrict__ bc, float* __restrict__ out)
{
  const int b = blockIdx.x;
  const int tid = threadIdx.x;
  const int wave = tid >> 6, lane = tid & 63;
  const float* xr = x + (size_t)b * SEQ * DIM;
  const float v = xr[tid];
  __shared__ float redm[4], redv[4], redc[4][4];
  float s = v;
  #pragma unroll
  for (int o = 32; o >= 1; o >>= 1) s += __shfl_xor(s, o);
  if (lane == 0) redm[wave] = s;
  __syncthreads();
  const float mean = (redm[0]+redm[1]+redm[2]+redm[3]) * (1.f/256.f);
  const float dv = v - mean;
  float q = dv * dv;
  #pragma unroll
  for (int o = 32; o >= 1; o >>= 1) q += __shfl_xor(q, o);
  if (lane == 0) redv[wave] = q;
  __syncthreads();
  const float var = (redv[0]+redv[1]+redv[2]+redv[3]) * (1.f/256.f);
  const float rs = rsqrtf(var + 1e-5f);
  const float yn = dv*rs*gf[tid] + bf[tid];
  float pc[4];
  #pragma unroll
  for (int cc = 0; cc < 4; ++cc) pc[cc] = yn * Wc[tid*4 + cc];
  #pragma unroll
  for (int cc = 0; cc < 4; ++cc) {
    #pragma unroll
    for (int o = 32; o >= 1; o >>= 1) pc[cc] += __shfl_xor(pc[cc], o);
  }
  if (lane == 0) {
    #pragma unroll
    for (int cc = 0; cc < 4; ++cc) redc[wave][cc] = pc[cc];
  }
  __syncthreads();
  if (tid < 4)
    out[b*4 + tid] = redc[0][tid] + redc[1][tid] + redc[2][tid] + redc[3][tid] + bc[tid];
}

extern "C" void kernel_launch(void* const* d_in, const int* in_sizes, int n_in,
                              void* d_out, int out_size, void* d_ws, size_t ws_size,
                              hipStream_t stream)
{
  const int*   ids    = (const int*)d_in[0];
  const int*   ngrams = (const int*)d_in[1];
  const float* tfidf  = (const float*)d_in[2];
  const float* emb    = (const float*)d_in[3];
  const float* pos    = (const float*)d_in[4];
  const float* bucket = (const float*)d_in[5];
  const float* Wq = (const float*)d_in[6];  const float* bq = (const float*)d_in[7];
  const float* Wk = (const float*)d_in[8];  const float* bk = (const float*)d_in[9];
  const float* Wv = (const float*)d_in[10]; const float* bv = (const float*)d_in[11];
  const float* Wo = (const float*)d_in[12]; const float* bo = (const float*)d_in[13];
  const float* g1 = (const float*)d_in[14]; const float* be1= (const float*)d_in[15];
  const float* g2 = (const float*)d_in[16]; const float* be2= (const float*)d_in[17];
  const float* W1 = (const float*)d_in[18]; const float* b1 = (const float*)d_in[19];
  const float* W2 = (const float*)d_in[20]; const float* b2 = (const float*)d_in[21];
  const float* alpha = (const float*)d_in[22];
  const float* gf = (const float*)d_in[23]; const float* bf = (const float*)d_in[24];
  const float* Wc = (const float*)d_in[25]; const float* bc = (const float*)d_in[26];

  uint8_t* base = (uint8_t*)d_ws;
  float*  x      = (float*)  base;                  //  8,388,608
  ushort* x2b    = (ushort*)(base + 8388608);       //  4,194,304
  ushort* qkh    = (ushort*)(base + 12582912);      //  8,388,608 (Q head-major, K at +QKSTRIDE)
  ushort* vtb    = (ushort*)(base + 20971520);      //  4,194,304 (V permuted)
  ushort* attb   = (ushort*)(base + 25165824);      //  4,194,304
  ushort* midb   = (ushort*)(base + 29360128);      // 16,777,216
  float*  bm2    = (float*) (base + 46137344);      //     65,536 (2 layers)
  ushort* WqkvT  = (ushort*)(base + 46202880);      //    786,432
  ushort* WoT    = (ushort*)(base + 46989312);      //    262,144
  ushort* W1T    = (ushort*)(base + 47251456);      //  1,048,576
  ushort* W2T    = (ushort*)(base + 48300032);      //  1,048,576  -> 49,348,608 total

  TDescs td;
  for (int l = 0; l < NL; ++l) {
    td.d[6*l+0] = { Wq + (size_t)l*DIM*DIM, WqkvT + (size_t)l*768*DIM +   0*DIM, DIM, DIM };
    td.d[6*l+1] = { Wk + (size_t)l*DIM*DIM, WqkvT + (size_t)l*768*DIM + 256*DIM, DIM, DIM };
    td.d[6*l+2] = { Wv + (size_t)l*DIM*DIM, WqkvT + (size_t)l*768*DIM + 512*DIM, DIM, DIM };
    td.d[6*l+3] = { Wo + (size_t)l*DIM*DIM, WoT  + (size_t)l*DIM*DIM,  DIM, DIM };
    td.d[6*l+4] = { W1 + (size_t)l*DIM*FFD, W1T  + (size_t)l*FFD*DIM,  DIM, FFD };
    td.d[6*l+5] = { W2 + (size_t)l*FFD*DIM, W2T  + (size_t)l*DIM*FFD,  FFD, DIM };
  }
  transpose_conv<<<dim3(32, 32, 12), 256, 0, stream>>>(td);

  embed_ln_kernel<<<TOK, 256, 0, stream>>>(
      ids, ngrams, tfidf, emb, pos, bucket, alpha, g1, be1, x, x2b, bm2);

  const dim3 gqkv(6, TOK/64), gff1(8, TOK/64), g64(4, TOK/64);
  for (int l = 0; l < NL; ++l) {
    if (l > 0)
      ln_bf16<<<TOK/4, 256, 0, stream>>>(x, g1 + l*DIM, be1 + l*DIM, x2b);
    gemm_mfma<256, 768, 3><<<gqkv, 256, 0, stream>>>(
        x2b, WqkvT + (size_t)l*768*DIM, bq + l*DIM, bk + l*DIM, bv + l*DIM, qkh, vtb);
    attn_mfma<<<2048, 256, 0, stream>>>(qkh, qkh + QKSTRIDE, vtb, bm2 + l*TOK, attb);
    gemm64_acc<256><<<g64, 256, 0, stream>>>(
        attb, WoT + (size_t)l*DIM*DIM, bo + l*DIM, x);
    ln_bf16<<<TOK/4, 256, 0, stream>>>(x, g2 + l*DIM, be2 + l*DIM, x2b);
    gemm_mfma<256, 1024, 1><<<gff1, 256, 0, stream>>>(
        x2b, W1T + (size_t)l*FFD*DIM, b1 + l*FFD, nullptr, nullptr, midb, nullptr);
    gemm64_acc<1024><<<g64, 256, 0, stream>>>(
        midb, W2T + (size_t)l*DIM*FFD, b2 + l*DIM, x);
  }
  cls_kernel<<<8, 256, 0, stream>>>(x, gf, bf, Wc, bc, (float*)d_out);
}

// Round 11
// 192.723 us; speedup vs baseline: 1.3198x; 1.0536x over previous
//
#include <hip/hip_runtime.h>
#include <hip/hip_bf16.h>
#include <math.h>

#define TOK 8192       // B*S
#define DIM 256
#define SEQ 1024
#define NH 8
#define FFD 1024
#define NL 2
#define VOCAB 32000
#define QKSTRIDE 2097152   // elems between Q and K head-major blocks

typedef short bf16x8 __attribute__((ext_vector_type(8)));
typedef float f32x4 __attribute__((ext_vector_type(4)));

__device__ __forceinline__ ushort f2bf(float f) {
  union { float f; uint32_t u; } v; v.f = f;
  uint32_t r = v.u + 0x7FFFu + ((v.u >> 16) & 1u);
  return (ushort)(r >> 16);
}

__device__ __forceinline__ float exp2_n(float x) {
  float r; asm("v_exp_f32 %0, %1" : "=v"(r) : "v"(x)); return r;
}

__device__ __forceinline__ uint32_t cvtpk(float lo, float hi) {
  uint32_t r; asm("v_cvt_pk_bf16_f32 %0, %1, %2" : "=v"(r) : "v"(lo), "v"(hi));
  return r;
}

__device__ __forceinline__ void gload_lds16(const ushort* gp, ushort* lp) {
  __builtin_amdgcn_global_load_lds(
      (const __attribute__((address_space(1))) void*)gp,
      (__attribute__((address_space(3))) void*)lp, 16, 0, 0);
}

// ---------------- embedding + ngram + tfidf bias + fused layer-0 LN ----------------
__global__ __launch_bounds__(256) void embed_ln_kernel(
    const int* __restrict__ ids, const int* __restrict__ ngram_ids,
    const float* __restrict__ tfidf, const float* __restrict__ emb,
    const float* __restrict__ pos, const float* __restrict__ bucket,
    const float* __restrict__ alpha, const float* __restrict__ g1,
    const float* __restrict__ be1,
    float* __restrict__ x, ushort* __restrict__ x2b, float* __restrict__ bm2)
{
  __shared__ int ngs[12];
  __shared__ float red[2][4];
  const int t = blockIdx.x;
  const int id = ids[t];
  int idc = id; if (idc < 0) idc = 0; if (idc > VOCAB-1) idc = VOCAB-1;
  if (threadIdx.x < 12) ngs[threadIdx.x] = ngram_ids[idc*12 + threadIdx.x];
  if (threadIdx.x == 0) {
    const float tf = tfidf[idc];
    const bool msk = (id == 0);
    const float l2e = 1.4426950408889634f;
    bm2[t]       = msk ? -1e30f : tf * alpha[0] * l2e;
    bm2[TOK + t] = msk ? -1e30f : tf * alpha[1] * l2e;
  }
  __syncthreads();
  const int d = threadIdx.x;
  const int s = t & (SEQ - 1);
  float v = emb[(size_t)id*DIM + d] + pos[s*DIM + d];
  float sum = 0.f; int cnt = 0;
  #pragma unroll
  for (int g = 0; g < 12; ++g) {
    const int ng = ngs[g];
    if (ng != 0) { sum += bucket[(size_t)ng*DIM + d]; cnt++; }
  }
  v += sum / fmaxf((float)cnt, 1.0f);
  x[(size_t)t*DIM + d] = v;
  // fused LN (layer 0, ln1)
  const int wave = d >> 6, lane = d & 63;
  float sm = v;
  #pragma unroll
  for (int o = 32; o >= 1; o >>= 1) sm += __shfl_xor(sm, o);
  if (lane == 0) red[0][wave] = sm;
  __syncthreads();
  const float mean = (red[0][0]+red[0][1]+red[0][2]+red[0][3]) * (1.f/256.f);
  const float dv = v - mean;
  float q = dv * dv;
  #pragma unroll
  for (int o = 32; o >= 1; o >>= 1) q += __shfl_xor(q, o);
  if (lane == 0) red[1][wave] = q;
  __syncthreads();
  const float var = (red[1][0]+red[1][1]+red[1][2]+red[1][3]) * (1.f/256.f);
  const float rs = rsqrtf(var + 1e-5f);
  x2b[(size_t)t*DIM + d] = f2bf(dv*rs*g1[d] + be1[d]);
}

// ---------------- layernorm -> bf16 ----------------
__global__ __launch_bounds__(256) void ln_bf16(
    const float* __restrict__ x, const float* __restrict__ g,
    const float* __restrict__ b, ushort* __restrict__ y)
{
  const int wave = threadIdx.x >> 6, lane = threadIdx.x & 63;
  const int row = blockIdx.x * 4 + wave;
  const float* xr = x + (size_t)row * DIM;
  float4 v = *reinterpret_cast<const float4*>(xr + lane*4);
  float s = v.x + v.y + v.z + v.w;
  #pragma unroll
  for (int o = 32; o >= 1; o >>= 1) s += __shfl_xor(s, o);
  const float mean = s * (1.f/256.f);
  const float dx0 = v.x-mean, dx1 = v.y-mean, dx2 = v.z-mean, dx3 = v.w-mean;
  float q = dx0*dx0 + dx1*dx1 + dx2*dx2 + dx3*dx3;
  #pragma unroll
  for (int o = 32; o >= 1; o >>= 1) q += __shfl_xor(q, o);
  const float rs = rsqrtf(q * (1.f/256.f) + 1e-5f);
  float4 gv = *reinterpret_cast<const float4*>(g + lane*4);
  float4 bv = *reinterpret_cast<const float4*>(b + lane*4);
  ushort4 o4;
  o4.x = f2bf(dx0*rs*gv.x + bv.x);
  o4.y = f2bf(dx1*rs*gv.y + bv.y);
  o4.z = f2bf(dx2*rs*gv.z + bv.z);
  o4.w = f2bf(dx3*rs*gv.w + bv.w);
  *reinterpret_cast<ushort4*>(y + (size_t)row*DIM + lane*4) = o4;
}

// ---------------- weight transpose + bf16: f32 [K][N] -> bf16 [N][K] ----------------
struct TDesc { const float* src; ushort* dst; int K; int N; };
struct TDescs { TDesc d[12]; };

__global__ __launch_bounds__(256) void transpose_conv(TDescs descs)
{
  const TDesc t = descs.d[blockIdx.z];
  const int k0 = blockIdx.x * 32, n0 = blockIdx.y * 32;
  if (k0 >= t.K || n0 >= t.N) return;
  __shared__ float tile[32][33];
  const int r = threadIdx.x >> 5, cc = threadIdx.x & 31;
  #pragma unroll
  for (int i = 0; i < 4; ++i)
    tile[r + i*8][cc] = t.src[(size_t)(k0 + r + i*8)*t.N + n0 + cc];
  __syncthreads();
  #pragma unroll
  for (int i = 0; i < 4; ++i)
    t.dst[(size_t)(n0 + r + i*8)*t.K + k0 + cc] = f2bf(tile[cc][r + i*8]);
}

// ---------------- bf16 MFMA GEMM, counted-vmcnt 3-buffer pipeline ----------------
// BM=64, BN=128, BK=32; 4 waves, wave w owns cols [w*32,+32); frags 4x2.
// 3 LDS buffers; per-wave 3 gload_lds per stage; waits vmcnt(6)->3->0 (never drains
// mid-loop); raw s_barrier pairs. K-accumulation order identical to R6/R10.
// MODE 1: relu + bf16 out;  MODE 3: qkv -> Q,K head-major + V permuted.
template<int KDIM, int NDIM, int MODE>
__global__ __launch_bounds__(256) void gemm_mfma(
    const ushort* __restrict__ A, const ushort* __restrict__ Bw,
    const float* __restrict__ bias0, const float* __restrict__ bias1,
    const float* __restrict__ bias2, void* __restrict__ Cout,
    ushort* __restrict__ vtb)
{
  __shared__ ushort Al[3][64*32];
  __shared__ ushort Bl[3][128*32];
  const int bm = blockIdx.y * 64, bn = blockIdx.x * 128;
  const int tid = threadIdx.x, w = tid >> 6, lane = tid & 63;
  const int g = lane >> 4, c = lane & 15;
  const int lrow = lane >> 2, lc8 = (lane & 3) << 3;
  const f32x4 fzero = {0.f, 0.f, 0.f, 0.f};
  f32x4 acc[4][2];
  #pragma unroll
  for (int m = 0; m < 4; ++m) { acc[m][0] = fzero; acc[m][1] = fzero; }

#define STAGE(buf, k0)                                                         \
  {                                                                            \
    _Pragma("unroll")                                                          \
    for (int ch = w; ch < 12; ch += 4) {                                       \
      if (ch < 4)                                                              \
        gload_lds16(A + (size_t)(bm + ch*16 + lrow)*KDIM + (k0) + lc8,         \
                    &Al[buf][ch*512]);                                         \
      else                                                                     \
        gload_lds16(Bw + (size_t)(bn + (ch-4)*16 + lrow)*KDIM + (k0) + lc8,    \
                    &Bl[buf][(ch-4)*512]);                                     \
    }                                                                          \
  }

#define COMPUTE(buf)                                                           \
  {                                                                            \
    bf16x8 af[4], bfr[2];                                                      \
    _Pragma("unroll")                                                          \
    for (int m = 0; m < 4; ++m)                                                \
      af[m] = *(const bf16x8*)&Al[buf][(m*16 + c)*32 + g*8];                   \
    _Pragma("unroll")                                                          \
    for (int n = 0; n < 2; ++n)                                                \
      bfr[n] = *(const bf16x8*)&Bl[buf][(w*32 + n*16 + c)*32 + g*8];           \
    _Pragma("unroll")                                                          \
    for (int m = 0; m < 4; ++m)                                                \
      _Pragma("unroll")                                                        \
      for (int n = 0; n < 2; ++n)                                              \
        acc[m][n] = __builtin_amdgcn_mfma_f32_16x16x32_bf16(af[m], bfr[n], acc[m][n], 0, 0, 0); \
  }

  STAGE(0, 0);
  STAGE(1, 32);
  STAGE(2, 64);
  int buf = 0;
  for (int k0 = 0; k0 + 64 < KDIM; k0 += 32) {
    asm volatile("s_waitcnt vmcnt(6)" ::: "memory");
    __builtin_amdgcn_s_barrier();
    COMPUTE(buf);
    asm volatile("s_waitcnt lgkmcnt(0)" ::: "memory");
    __builtin_amdgcn_s_barrier();
    if (k0 + 96 < KDIM) STAGE(buf, k0 + 96);
    buf = (buf == 2) ? 0 : buf + 1;
  }
  asm volatile("s_waitcnt vmcnt(3)" ::: "memory");
  __builtin_amdgcn_s_barrier();
  COMPUTE(buf);
  buf = (buf == 2) ? 0 : buf + 1;
  asm volatile("s_waitcnt vmcnt(0)" ::: "memory");
  __builtin_amdgcn_s_barrier();
  COMPUTE(buf);
#undef STAGE
#undef COMPUTE

  #pragma unroll
  for (int m = 0; m < 4; ++m) {
    const int row0 = bm + m*16 + g*4;
    #pragma unroll
    for (int n = 0; n < 2; ++n) {
      const int col = bn + w*32 + n*16 + c;
      if (MODE == 1) {
        const float bb = bias0[col];
        #pragma unroll
        for (int r = 0; r < 4; ++r) {
          const float vv = fmaxf(acc[m][n][r] + bb, 0.f);
          const float other = __shfl_xor(vv, 1);
          if ((c & 1) == 0) {
            const uint32_t word = (uint32_t)f2bf(vv) | ((uint32_t)f2bf(other) << 16);
            *(uint32_t*)((ushort*)Cout + (size_t)(row0 + r)*NDIM + col) = word;
          }
        }
      } else {  // MODE 3
        const int b_ = row0 >> 10, s = row0 & (SEQ - 1);
        if (col < 512) {
          const int hd = col & 255;
          const int hh = hd >> 5, d = hd & 31;
          const float bb = (col < 256) ? bias0[hd] : bias1[hd];
          ushort* dst = (ushort*)Cout + (col < 256 ? 0 : QKSTRIDE)
                      + (((size_t)(b_*NH + hh)*SEQ + s) << 5) + d;
          #pragma unroll
          for (int r = 0; r < 4; ++r) {
            const float vv = acc[m][n][r] + bb;
            const float other = __shfl_xor(vv, 1);
            if ((c & 1) == 0) {
              const uint32_t word = (uint32_t)f2bf(vv) | ((uint32_t)f2bf(other) << 16);
              *(uint32_t*)(dst + (r << 5)) = word;
            }
          }
        } else {
          // V: permuted k-slot layout. position p = g'*8 + hi*4 + rr <-> key 16*hi+4*g'+rr
          const int hd = col - 512;
          const int hh = hd >> 5, d = hd & 31;
          const float bb = bias2[hd];
          const int sg = s >> 5, a = (s & 31) >> 2;
          const int pbase = (a & 3)*8 + (a >> 2)*4;
          ushort4 w4;
          w4.x = f2bf(acc[m][n][0] + bb);
          w4.y = f2bf(acc[m][n][1] + bb);
          w4.z = f2bf(acc[m][n][2] + bb);
          w4.w = f2bf(acc[m][n][3] + bb);
          *(ushort4*)(vtb + (((size_t)((b_*NH + hh)*32 + sg)*32 + d) << 5) + pbase) = w4;
        }
      }
    }
  }
}

// ---------------- 64x64-tile accumulate GEMM (N=256), counted-vmcnt 3-buffer ----------------
// per-wave 2 gload_lds per stage; waits vmcnt(4)->2->0.
template<int KDIM>
__global__ __launch_bounds__(256) void gemm64_acc(
    const ushort* __restrict__ A, const ushort* __restrict__ Bw,
    const float* __restrict__ bias, float* __restrict__ C)
{
  __shared__ ushort Al[3][64*32];
  __shared__ ushort Bl[3][64*32];
  const int bm = blockIdx.y * 64, bn = blockIdx.x * 64;
  const int tid = threadIdx.x, w = tid >> 6, lane = tid & 63;
  const int wm = w >> 1, wn = w & 1;
  const int g = lane >> 4, c = lane & 15;
  const int lrow = tid >> 2, lc8 = (tid & 3) << 3;
  const f32x4 fzero = {0.f, 0.f, 0.f, 0.f};
  f32x4 acc[2][2];
  acc[0][0] = fzero; acc[0][1] = fzero; acc[1][0] = fzero; acc[1][1] = fzero;

#define STAGE64(buf, k0)                                                       \
  {                                                                            \
    gload_lds16(A  + (size_t)(bm + lrow)*KDIM + (k0) + lc8,                    \
                &Al[buf][lrow*32 + lc8]);                                      \
    gload_lds16(Bw + (size_t)(bn + lrow)*KDIM + (k0) + lc8,                    \
                &Bl[buf][lrow*32 + lc8]);                                      \
  }

#define COMPUTE64(buf)                                                         \
  {                                                                            \
    bf16x8 af[2], bfr[2];                                                      \
    _Pragma("unroll")                                                          \
    for (int m = 0; m < 2; ++m)                                                \
      af[m] = *(const bf16x8*)&Al[buf][(wm*32 + m*16 + c)*32 + g*8];           \
    _Pragma("unroll")                                                          \
    for (int n = 0; n < 2; ++n)                                                \
      bfr[n] = *(const bf16x8*)&Bl[buf][(wn*32 + n*16 + c)*32 + g*8];          \
    _Pragma("unroll")                                                          \
    for (int m = 0; m < 2; ++m)                                                \
      _Pragma("unroll")                                                        \
      for (int n = 0; n < 2; ++n)                                              \
        acc[m][n] = __builtin_amdgcn_mfma_f32_16x16x32_bf16(af[m], bfr[n], acc[m][n], 0, 0, 0); \
  }

  STAGE64(0, 0);
  STAGE64(1, 32);
  STAGE64(2, 64);
  int buf = 0;
  for (int k0 = 0; k0 + 64 < KDIM; k0 += 32) {
    asm volatile("s_waitcnt vmcnt(4)" ::: "memory");
    __builtin_amdgcn_s_barrier();
    COMPUTE64(buf);
    asm volatile("s_waitcnt lgkmcnt(0)" ::: "memory");
    __builtin_amdgcn_s_barrier();
    if (k0 + 96 < KDIM) STAGE64(buf, k0 + 96);
    buf = (buf == 2) ? 0 : buf + 1;
  }
  asm volatile("s_waitcnt vmcnt(2)" ::: "memory");
  __builtin_amdgcn_s_barrier();
  COMPUTE64(buf);
  buf = (buf == 2) ? 0 : buf + 1;
  asm volatile("s_waitcnt vmcnt(0)" ::: "memory");
  __builtin_amdgcn_s_barrier();
  COMPUTE64(buf);
#undef STAGE64
#undef COMPUTE64

  #pragma unroll
  for (int m = 0; m < 2; ++m) {
    const int row0 = bm + wm*32 + m*16 + g*4;
    #pragma unroll
    for (int n = 0; n < 2; ++n) {
      const int col = bn + wn*32 + n*16 + c;
      const float bb = bias[col];
      #pragma unroll
      for (int r = 0; r < 4; ++r)
        C[(size_t)(row0 + r)*DIM + col] += acc[m][n][r] + bb;
    }
  }
}

// ---------------- flash attention: 32 q-rows/block, 4-way key split, max-free softmax ----------------
// grid 2048 x 256 threads; bijective XCD chunking; block = (b,h,q32), wave w = keys [w*256,+256).
__global__ __launch_bounds__(256) void attn_mfma(
    const ushort* __restrict__ qh, const ushort* __restrict__ kh,
    const ushort* __restrict__ vph, const float* __restrict__ bm2l,
    ushort* __restrict__ O)
{
  const int bid = blockIdx.x;
  const int lin = ((bid & 7) << 8) + (bid >> 3);       // bijective (2048 % 8 == 0)
  const int tid = threadIdx.x, w = tid >> 6, lane = tid & 63;
  const int qw = lin & 31, h = (lin >> 5) & 7, b = lin >> 8;
  const int qb = qw << 5;
  const float scale2 = 0.17677669529663687f * 1.4426950408889634f;  // rsqrt(32)*log2e
  const int g = lane >> 4, c = lane & 15;
  const f32x4 fzero = {0.f, 0.f, 0.f, 0.f};
  const size_t bh = (size_t)(b*NH + h);

  const bf16x8 qf0 = *(const bf16x8*)(qh + ((bh*SEQ + qb + c)      << 5) + g*8);
  const bf16x8 qf1 = *(const bf16x8*)(qh + ((bh*SEQ + qb + 16 + c) << 5) + g*8);
  const ushort* kbase = kh  + ((bh*SEQ) << 5) + g*8;   // + key*32
  const ushort* vbase = vph + ((bh*SEQ) << 5) + g*8;   // + (sg*32 + d)*32
  const float*  bmb   = bm2l + b*SEQ;

  f32x4 oacc[2][2];                                    // [q][ds]
  oacc[0][0] = fzero; oacc[0][1] = fzero; oacc[1][0] = fzero; oacc[1][1] = fzero;
  float l0 = 0.f, l1 = 0.f;

  bf16x8 kfA[4], kfB[4];
  bf16x8 vfA[2][2], vfB[2][2];
  f32x4 bbA[4], bbB[4];

#define LOADT(kt, kf, vf, bb)                                                  \
  {                                                                            \
    _Pragma("unroll")                                                          \
    for (int ks = 0; ks < 4; ++ks) {                                           \
      kf[ks] = *(const bf16x8*)(kbase + (((kt) + ks*16 + c) << 5));            \
      bb[ks] = *(const f32x4*)(bmb + (kt) + ks*16 + g*4);                      \
    }                                                                          \
    _Pragma("unroll")                                                          \
    for (int ds_ = 0; ds_ < 2; ++ds_)                                          \
      _Pragma("unroll")                                                        \
      for (int sg = 0; sg < 2; ++sg)                                           \
        vf[ds_][sg] = *(const bf16x8*)(vbase +                                 \
            (((((kt) >> 5) + sg)*32 + ds_*16 + c) << 5));                      \
  }

#define ATILE(kf, vf, bb)                                                      \
  {                                                                            \
    f32x4 sf0[4], sf1[4];                                                      \
    __builtin_amdgcn_s_setprio(1);                                             \
    _Pragma("unroll")                                                          \
    for (int ks = 0; ks < 4; ++ks)                                             \
      sf0[ks] = __builtin_amdgcn_mfma_f32_16x16x32_bf16(kf[ks], qf0, fzero, 0, 0, 0); \
    _Pragma("unroll")                                                          \
    for (int ks = 0; ks < 4; ++ks)                                             \
      sf1[ks] = __builtin_amdgcn_mfma_f32_16x16x32_bf16(kf[ks], qf1, fzero, 0, 0, 0); \
    __builtin_amdgcn_s_setprio(0);                                             \
    float e0[4][4], e1[4][4];                                                  \
    _Pragma("unroll")                                                          \
    for (int ks = 0; ks < 4; ++ks)                                             \
      _Pragma("unroll")                                                        \
      for (int r = 0; r < 4; ++r) {                                            \
        e0[ks][r] = exp2_n(fmaf(sf0[ks][r], scale2, bb[ks][r]));               \
        e1[ks][r] = exp2_n(fmaf(sf1[ks][r], scale2, bb[ks][r]));               \
      }                                                                        \
    float a0 = 0.f, a1 = 0.f, a2 = 0.f, a3 = 0.f;                              \
    _Pragma("unroll")                                                          \
    for (int r = 0; r < 4; ++r) {                                              \
      a0 += e0[0][r] + e0[1][r]; a1 += e0[2][r] + e0[3][r];                    \
      a2 += e1[0][r] + e1[1][r]; a3 += e1[2][r] + e1[3][r];                    \
    }                                                                          \
    l0 += a0 + a1; l1 += a2 + a3;                                              \
    union { bf16x8 v; uint32_t u[4]; } p00, p01, p10, p11;                     \
    p00.u[0] = cvtpk(e0[0][0], e0[0][1]); p00.u[1] = cvtpk(e0[0][2], e0[0][3]);\
    p00.u[2] = cvtpk(e0[1][0], e0[1][1]); p00.u[3] = cvtpk(e0[1][2], e0[1][3]);\
    p01.u[0] = cvtpk(e0[2][0], e0[2][1]); p01.u[1] = cvtpk(e0[2][2], e0[2][3]);\
    p01.u[2] = cvtpk(e0[3][0], e0[3][1]); p01.u[3] = cvtpk(e0[3][2], e0[3][3]);\
    p10.u[0] = cvtpk(e1[0][0], e1[0][1]); p10.u[1] = cvtpk(e1[0][2], e1[0][3]);\
    p10.u[2] = cvtpk(e1[1][0], e1[1][1]); p10.u[3] = cvtpk(e1[1][2], e1[1][3]);\
    p11.u[0] = cvtpk(e1[2][0], e1[2][1]); p11.u[1] = cvtpk(e1[2][2], e1[2][3]);\
    p11.u[2] = cvtpk(e1[3][0], e1[3][1]); p11.u[3] = cvtpk(e1[3][2], e1[3][3]);\
    __builtin_amdgcn_s_setprio(1);                                             \
    oacc[0][0] = __builtin_amdgcn_mfma_f32_16x16x32_bf16(vf[0][0], p00.v, oacc[0][0], 0, 0, 0); \
    oacc[0][1] = __builtin_amdgcn_mfma_f32_16x16x32_bf16(vf[1][0], p00.v, oacc[0][1], 0, 0, 0); \
    oacc[1][0] = __builtin_amdgcn_mfma_f32_16x16x32_bf16(vf[0][0], p10.v, oacc[1][0], 0, 0, 0); \
    oacc[1][1] = __builtin_amdgcn_mfma_f32_16x16x32_bf16(vf[1][0], p10.v, oacc[1][1], 0, 0, 0); \
    oacc[0][0] = __builtin_amdgcn_mfma_f32_16x16x32_bf16(vf[0][1], p01.v, oacc[0][0], 0, 0, 0); \
    oacc[0][1] = __builtin_amdgcn_mfma_f32_16x16x32_bf16(vf[1][1], p01.v, oacc[0][1], 0, 0, 0); \
    oacc[1][0] = __builtin_amdgcn_mfma_f32_16x16x32_bf16(vf[0][1], p11.v, oacc[1][0], 0, 0, 0); \
    oacc[1][1] = __builtin_amdgcn_mfma_f32_16x16x32_bf16(vf[1][1], p11.v, oacc[1][1], 0, 0, 0); \
    __builtin_amdgcn_s_setprio(0);                                             \
  }

  const int kt0 = w << 8;
  LOADT(kt0, kfA, vfA, bbA);
  LOADT(kt0 + 64, kfB, vfB, bbB);
  ATILE(kfA, vfA, bbA);
  LOADT(kt0 + 128, kfA, vfA, bbA);
  ATILE(kfB, vfB, bbB);
  LOADT(kt0 + 192, kfB, vfB, bbB);
  ATILE(kfA, vfA, bbA);
  ATILE(kfB, vfB, bbB);
#undef LOADT
#undef ATILE

  // ---- in-block SUM combine of the 4 key-quarter partials (no max -> no rescale) ----
  __shared__ float Lo[4][64][19];
  #pragma unroll
  for (int q = 0; q < 2; ++q)
    #pragma unroll
    for (int ds_ = 0; ds_ < 2; ++ds_)
      #pragma unroll
      for (int i = 0; i < 4; ++i)
        Lo[w][lane][q*8 + ds_*4 + i] = oacc[q][ds_][i];
  Lo[w][lane][16] = l0;
  Lo[w][lane][17] = l1;
  __syncthreads();
  if (w < 2) {
    const int q = w;
    float o[8] = {0.f,0.f,0.f,0.f,0.f,0.f,0.f,0.f};
    float ls = 0.f;
    #pragma unroll
    for (int ww = 0; ww < 4; ++ww) {
      ls += Lo[ww][lane][16 + q];
      #pragma unroll
      for (int i = 0; i < 8; ++i) o[i] += Lo[ww][lane][q*8 + i];
    }
    ls += __shfl_xor(ls, 16);
    ls += __shfl_xor(ls, 32);
    const float inv = 1.f / ls;
    ushort* orow = O + (size_t)(b*SEQ + qb + q*16 + c)*DIM + h*32 + g*4;
    const uint32_t w0 = (uint32_t)f2bf(o[0]*inv) | ((uint32_t)f2bf(o[1]*inv) << 16);
    const uint32_t w1 = (uint32_t)f2bf(o[2]*inv) | ((uint32_t)f2bf(o[3]*inv) << 16);
    const uint32_t w2 = (uint32_t)f2bf(o[4]*inv) | ((uint32_t)f2bf(o[5]*inv) << 16);
    const uint32_t w3 = (uint32_t)f2bf(o[6]*inv) | ((uint32_t)f2bf(o[7]*inv) << 16);
    *(uint32_t*)(orow)      = w0;
    *(uint32_t*)(orow + 2)  = w1;
    *(uint32_t*)(orow + 16) = w2;
    *(uint32_t*)(orow + 18) = w3;
  }
}

// ---------------- final LN (row 0 per batch) + classifier ----------------
__global__ __launch_bounds__(256) void cls_kernel(
    const float* __restrict__ x, const float* __restrict__ gf,
    const float* __restrict__ bf, const float* __restrict__ Wc,
    const float* __restrict__ bc, float* __restrict__ out)
{
  const int b = blockIdx.x;
  const int tid = threadIdx.x;
  const int wave = tid >> 6, lane = tid & 63;
  const float* xr = x + (size_t)b * SEQ * DIM;
  const float v = xr[tid];
  __shared__ float redm[4], redv[4], redc[4][4];
  float s = v;
  #pragma unroll
  for (int o = 32; o >= 1; o >>= 1) s += __shfl_xor(s, o);
  if (lane == 0) redm[wave] = s;
  __syncthreads();
  const float mean = (redm[0]+redm[1]+redm[2]+redm[3]) * (1.f/256.f);
  const float dv = v - mean;
  float q = dv * dv;
  #pragma unroll
  for (int o = 32; o >= 1; o >>= 1) q += __shfl_xor(q, o);
  if (lane == 0) redv[wave] = q;
  __syncthreads();
  const float var = (redv[0]+redv[1]+redv[2]+redv[3]) * (1.f/256.f);
  const float rs = rsqrtf(var + 1e-5f);
  const float yn = dv*rs*gf[tid] + bf[tid];
  float pc[4];
  #pragma unroll
  for (int cc = 0; cc < 4; ++cc) pc[cc] = yn * Wc[tid*4 + cc];
  #pragma unroll
  for (int cc = 0; cc < 4; ++cc) {
    #pragma unroll
    for (int o = 32; o >= 1; o >>= 1) pc[cc] += __shfl_xor(pc[cc], o);
  }
  if (lane == 0) {
    #pragma unroll
    for (int cc = 0; cc < 4; ++cc) redc[wave][cc] = pc[cc];
  }
  __syncthreads();
  if (tid < 4)
    out[b*4 + tid] = redc[0][tid] + redc[1][tid] + redc[2][tid] + redc[3][tid] + bc[tid];
}

extern "C" void kernel_launch(void* const* d_in, const int* in_sizes, int n_in,
                              void* d_out, int out_size, void* d_ws, size_t ws_size,
                              hipStream_t stream)
{
  const int*   ids    = (const int*)d_in[0];
  const int*   ngrams = (const int*)d_in[1];
  const float* tfidf  = (const float*)d_in[2];
  const float* emb    = (const float*)d_in[3];
  const float* pos    = (const float*)d_in[4];
  const float* bucket = (const float*)d_in[5];
  const float* Wq = (const float*)d_in[6];  const float* bq = (const float*)d_in[7];
  const float* Wk = (const float*)d_in[8];  const float* bk = (const float*)d_in[9];
  const float* Wv = (const float*)d_in[10]; const float* bv = (const float*)d_in[11];
  const float* Wo = (const float*)d_in[12]; const float* bo = (const float*)d_in[13];
  const float* g1 = (const float*)d_in[14]; const float* be1= (const float*)d_in[15];
  const float* g2 = (const float*)d_in[16]; const float* be2= (const float*)d_in[17];
  const float* W1 = (const float*)d_in[18]; const float* b1 = (const float*)d_in[19];
  const float* W2 = (const float*)d_in[20]; const float* b2 = (const float*)d_in[21];
  const float* alpha = (const float*)d_in[22];
  const float* gf = (const float*)d_in[23]; const float* bf = (const float*)d_in[24];
  const float* Wc = (const float*)d_in[25]; const float* bc = (const float*)d_in[26];

  uint8_t* base = (uint8_t*)d_ws;
  float*  x      = (float*)  base;                  //  8,388,608
  ushort* x2b    = (ushort*)(base + 8388608);       //  4,194,304
  ushort* qkh    = (ushort*)(base + 12582912);      //  8,388,608 (Q head-major, K at +QKSTRIDE)
  ushort* vtb    = (ushort*)(base + 20971520);      //  4,194,304 (V permuted)
  ushort* attb   = (ushort*)(base + 25165824);      //  4,194,304
  ushort* midb   = (ushort*)(base + 29360128);      // 16,777,216
  float*  bm2    = (float*) (base + 46137344);      //     65,536 (2 layers)
  ushort* WqkvT  = (ushort*)(base + 46202880);      //    786,432
  ushort* WoT    = (ushort*)(base + 46989312);      //    262,144
  ushort* W1T    = (ushort*)(base + 47251456);      //  1,048,576
  ushort* W2T    = (ushort*)(base + 48300032);      //  1,048,576  -> 49,348,608 total

  TDescs td;
  for (int l = 0; l < NL; ++l) {
    td.d[6*l+0] = { Wq + (size_t)l*DIM*DIM, WqkvT + (size_t)l*768*DIM +   0*DIM, DIM, DIM };
    td.d[6*l+1] = { Wk + (size_t)l*DIM*DIM, WqkvT + (size_t)l*768*DIM + 256*DIM, DIM, DIM };
    td.d[6*l+2] = { Wv + (size_t)l*DIM*DIM, WqkvT + (size_t)l*768*DIM + 512*DIM, DIM, DIM };
    td.d[6*l+3] = { Wo + (size_t)l*DIM*DIM, WoT  + (size_t)l*DIM*DIM,  DIM, DIM };
    td.d[6*l+4] = { W1 + (size_t)l*DIM*FFD, W1T  + (size_t)l*FFD*DIM,  DIM, FFD };
    td.d[6*l+5] = { W2 + (size_t)l*FFD*DIM, W2T  + (size_t)l*DIM*FFD,  FFD, DIM };
  }
  transpose_conv<<<dim3(32, 32, 12), 256, 0, stream>>>(td);

  embed_ln_kernel<<<TOK, 256, 0, stream>>>(
      ids, ngrams, tfidf, emb, pos, bucket, alpha, g1, be1, x, x2b, bm2);

  const dim3 gqkv(6, TOK/64), gff1(8, TOK/64), g64(4, TOK/64);
  for (int l = 0; l < NL; ++l) {
    if (l > 0)
      ln_bf16<<<TOK/4, 256, 0, stream>>>(x, g1 + l*DIM, be1 + l*DIM, x2b);
    gemm_mfma<256, 768, 3><<<gqkv, 256, 0, stream>>>(
        x2b, WqkvT + (size_t)l*768*DIM, bq + l*DIM, bk + l*DIM, bv + l*DIM, qkh, vtb);
    attn_mfma<<<2048, 256, 0, stream>>>(qkh, qkh + QKSTRIDE, vtb, bm2 + l*TOK, attb);
    gemm64_acc<256><<<g64, 256, 0, stream>>>(
        attb, WoT + (size_t)l*DIM*DIM, bo + l*DIM, x);
    ln_bf16<<<TOK/4, 256, 0, stream>>>(x, g2 + l*DIM, be2 + l*DIM, x2b);
    gemm_mfma<256, 1024, 1><<<gff1, 256, 0, stream>>>(
        x2b, W1T + (size_t)l*FFD*DIM, b1 + l*FFD, nullptr, nullptr, midb, nullptr);
    gemm64_acc<1024><<<g64, 256, 0, stream>>>(
        midb, W2T + (size_t)l*DIM*FFD, b2 + l*DIM, x);
  }
  cls_kernel<<<8, 256, 0, stream>>>(x, gf, bf, Wc, bc, (float*)d_out);
}

// Round 12
// 173.060 us; speedup vs baseline: 1.4697x; 1.1136x over previous
//
#include <hip/hip_runtime.h>
#include <hip/hip_bf16.h>
#include <math.h>

#define TOK 8192       // B*S
#define DIM 256
#define SEQ 1024
#define NH 8
#define FFD 1024
#define NL 2
#define VOCAB 32000
#define QKSTRIDE 2097152   // elems between Q and K head-major blocks

typedef short bf16x8 __attribute__((ext_vector_type(8)));
typedef float f32x4 __attribute__((ext_vector_type(4)));

__device__ __forceinline__ ushort f2bf(float f) {
  union { float f; uint32_t u; } v; v.f = f;
  uint32_t r = v.u + 0x7FFFu + ((v.u >> 16) & 1u);
  return (ushort)(r >> 16);
}

__device__ __forceinline__ float bf2f(ushort u) {
  union { uint32_t u; float f; } v; v.u = (uint32_t)u << 16; return v.f;
}

__device__ __forceinline__ float exp2_n(float x) {
  float r; asm("v_exp_f32 %0, %1" : "=v"(r) : "v"(x)); return r;
}

__device__ __forceinline__ uint32_t cvtpk(float lo, float hi) {
  uint32_t r; asm("v_cvt_pk_bf16_f32 %0, %1, %2" : "=v"(r) : "v"(lo), "v"(hi));
  return r;
}

__device__ __forceinline__ void gload_lds16(const ushort* gp, ushort* lp) {
  __builtin_amdgcn_global_load_lds(
      (const __attribute__((address_space(1))) void*)gp,
      (__attribute__((address_space(3))) void*)lp, 16, 0, 0);
}

// ---------------- embedding + ngram + tfidf bias + fused layer-0 LN ----------------
__global__ __launch_bounds__(256) void embed_ln_kernel(
    const int* __restrict__ ids, const int* __restrict__ ngram_ids,
    const float* __restrict__ tfidf, const float* __restrict__ emb,
    const float* __restrict__ pos, const float* __restrict__ bucket,
    const float* __restrict__ alpha, const float* __restrict__ g1,
    const float* __restrict__ be1,
    float* __restrict__ x, ushort* __restrict__ x2b, float* __restrict__ bm2)
{
  __shared__ int ngs[12];
  __shared__ float red[2][4];
  const int t = blockIdx.x;
  const int id = ids[t];
  int idc = id; if (idc < 0) idc = 0; if (idc > VOCAB-1) idc = VOCAB-1;
  if (threadIdx.x < 12) ngs[threadIdx.x] = ngram_ids[idc*12 + threadIdx.x];
  if (threadIdx.x == 0) {
    const float tf = tfidf[idc];
    const bool msk = (id == 0);
    const float l2e = 1.4426950408889634f;
    bm2[t]       = msk ? -1e30f : tf * alpha[0] * l2e;
    bm2[TOK + t] = msk ? -1e30f : tf * alpha[1] * l2e;
  }
  __syncthreads();
  const int d = threadIdx.x;
  const int s = t & (SEQ - 1);
  float v = emb[(size_t)id*DIM + d] + pos[s*DIM + d];
  float sum = 0.f; int cnt = 0;
  #pragma unroll
  for (int g = 0; g < 12; ++g) {
    const int ng = ngs[g];
    if (ng != 0) { sum += bucket[(size_t)ng*DIM + d]; cnt++; }
  }
  v += sum / fmaxf((float)cnt, 1.0f);
  x[(size_t)t*DIM + d] = v;
  // fused LN (layer 0, ln1)
  const int wave = d >> 6, lane = d & 63;
  float sm = v;
  #pragma unroll
  for (int o = 32; o >= 1; o >>= 1) sm += __shfl_xor(sm, o);
  if (lane == 0) red[0][wave] = sm;
  __syncthreads();
  const float mean = (red[0][0]+red[0][1]+red[0][2]+red[0][3]) * (1.f/256.f);
  const float dv = v - mean;
  float q = dv * dv;
  #pragma unroll
  for (int o = 32; o >= 1; o >>= 1) q += __shfl_xor(q, o);
  if (lane == 0) red[1][wave] = q;
  __syncthreads();
  const float var = (red[1][0]+red[1][1]+red[1][2]+red[1][3]) * (1.f/256.f);
  const float rs = rsqrtf(var + 1e-5f);
  x2b[(size_t)t*DIM + d] = f2bf(dv*rs*g1[d] + be1[d]);
}

// ---------------- layernorm -> bf16 ----------------
__global__ __launch_bounds__(256) void ln_bf16(
    const float* __restrict__ x, const float* __restrict__ g,
    const float* __restrict__ b, ushort* __restrict__ y)
{
  const int wave = threadIdx.x >> 6, lane = threadIdx.x & 63;
  const int row = blockIdx.x * 4 + wave;
  const float* xr = x + (size_t)row * DIM;
  float4 v = *reinterpret_cast<const float4*>(xr + lane*4);
  float s = v.x + v.y + v.z + v.w;
  #pragma unroll
  for (int o = 32; o >= 1; o >>= 1) s += __shfl_xor(s, o);
  const float mean = s * (1.f/256.f);
  const float dx0 = v.x-mean, dx1 = v.y-mean, dx2 = v.z-mean, dx3 = v.w-mean;
  float q = dx0*dx0 + dx1*dx1 + dx2*dx2 + dx3*dx3;
  #pragma unroll
  for (int o = 32; o >= 1; o >>= 1) q += __shfl_xor(q, o);
  const float rs = rsqrtf(q * (1.f/256.f) + 1e-5f);
  float4 gv = *reinterpret_cast<const float4*>(g + lane*4);
  float4 bv = *reinterpret_cast<const float4*>(b + lane*4);
  ushort4 o4;
  o4.x = f2bf(dx0*rs*gv.x + bv.x);
  o4.y = f2bf(dx1*rs*gv.y + bv.y);
  o4.z = f2bf(dx2*rs*gv.z + bv.z);
  o4.w = f2bf(dx3*rs*gv.w + bv.w);
  *reinterpret_cast<ushort4*>(y + (size_t)row*DIM + lane*4) = o4;
}

// ---------------- weight transpose + bf16: f32 [K][N] -> bf16 [N][K] ----------------
struct TDesc { const float* src; ushort* dst; int K; int N; };
struct TDescs { TDesc d[12]; };

__global__ __launch_bounds__(256) void transpose_conv(TDescs descs)
{
  const TDesc t = descs.d[blockIdx.z];
  const int k0 = blockIdx.x * 32, n0 = blockIdx.y * 32;
  if (k0 >= t.K || n0 >= t.N) return;
  __shared__ float tile[32][33];
  const int r = threadIdx.x >> 5, cc = threadIdx.x & 31;
  #pragma unroll
  for (int i = 0; i < 4; ++i)
    tile[r + i*8][cc] = t.src[(size_t)(k0 + r + i*8)*t.N + n0 + cc];
  __syncthreads();
  #pragma unroll
  for (int i = 0; i < 4; ++i)
    t.dst[(size_t)(n0 + r + i*8)*t.K + k0 + cc] = f2bf(tile[cc][r + i*8]);
}

// ---------------- bf16 MFMA GEMM, counted-vmcnt 3-buffer pipeline ----------------
// BM=64, BN=128, BK=32; 4 waves, wave w owns cols [w*32,+32); frags 4x2.
// MODE 1: relu + bf16 out;
// MODE 3: qkv -> Q,K head-major + V permuted (l=0 path);
// MODE 4: K,V BOTH head-major (layer-2 tail path; Cout=K base, vtb=V base).
template<int KDIM, int NDIM, int MODE>
__global__ __launch_bounds__(256) void gemm_mfma(
    const ushort* __restrict__ A, const ushort* __restrict__ Bw,
    const float* __restrict__ bias0, const float* __restrict__ bias1,
    const float* __restrict__ bias2, void* __restrict__ Cout,
    ushort* __restrict__ vtb)
{
  __shared__ ushort Al[3][64*32];
  __shared__ ushort Bl[3][128*32];
  const int bm = blockIdx.y * 64, bn = blockIdx.x * 128;
  const int tid = threadIdx.x, w = tid >> 6, lane = tid & 63;
  const int g = lane >> 4, c = lane & 15;
  const int lrow = lane >> 2, lc8 = (lane & 3) << 3;
  const f32x4 fzero = {0.f, 0.f, 0.f, 0.f};
  f32x4 acc[4][2];
  #pragma unroll
  for (int m = 0; m < 4; ++m) { acc[m][0] = fzero; acc[m][1] = fzero; }

#define STAGE(buf, k0)                                                         \
  {                                                                            \
    _Pragma("unroll")                                                          \
    for (int ch = w; ch < 12; ch += 4) {                                       \
      if (ch < 4)                                                              \
        gload_lds16(A + (size_t)(bm + ch*16 + lrow)*KDIM + (k0) + lc8,         \
                    &Al[buf][ch*512]);                                         \
      else                                                                     \
        gload_lds16(Bw + (size_t)(bn + (ch-4)*16 + lrow)*KDIM + (k0) + lc8,    \
                    &Bl[buf][(ch-4)*512]);                                     \
    }                                                                          \
  }

#define COMPUTE(buf)                                                           \
  {                                                                            \
    bf16x8 af[4], bfr[2];                                                      \
    _Pragma("unroll")                                                          \
    for (int m = 0; m < 4; ++m)                                                \
      af[m] = *(const bf16x8*)&Al[buf][(m*16 + c)*32 + g*8];                   \
    _Pragma("unroll")                                                          \
    for (int n = 0; n < 2; ++n)                                                \
      bfr[n] = *(const bf16x8*)&Bl[buf][(w*32 + n*16 + c)*32 + g*8];           \
    _Pragma("unroll")                                                          \
    for (int m = 0; m < 4; ++m)                                                \
      _Pragma("unroll")                                                        \
      for (int n = 0; n < 2; ++n)                                              \
        acc[m][n] = __builtin_amdgcn_mfma_f32_16x16x32_bf16(af[m], bfr[n], acc[m][n], 0, 0, 0); \
  }

  STAGE(0, 0);
  STAGE(1, 32);
  STAGE(2, 64);
  int buf = 0;
  for (int k0 = 0; k0 + 64 < KDIM; k0 += 32) {
    asm volatile("s_waitcnt vmcnt(6)" ::: "memory");
    __builtin_amdgcn_s_barrier();
    COMPUTE(buf);
    asm volatile("s_waitcnt lgkmcnt(0)" ::: "memory");
    __builtin_amdgcn_s_barrier();
    if (k0 + 96 < KDIM) STAGE(buf, k0 + 96);
    buf = (buf == 2) ? 0 : buf + 1;
  }
  asm volatile("s_waitcnt vmcnt(3)" ::: "memory");
  __builtin_amdgcn_s_barrier();
  COMPUTE(buf);
  buf = (buf == 2) ? 0 : buf + 1;
  asm volatile("s_waitcnt vmcnt(0)" ::: "memory");
  __builtin_amdgcn_s_barrier();
  COMPUTE(buf);
#undef STAGE
#undef COMPUTE

  #pragma unroll
  for (int m = 0; m < 4; ++m) {
    const int row0 = bm + m*16 + g*4;
    #pragma unroll
    for (int n = 0; n < 2; ++n) {
      const int col = bn + w*32 + n*16 + c;
      if (MODE == 1) {
        const float bb = bias0[col];
        #pragma unroll
        for (int r = 0; r < 4; ++r) {
          const float vv = fmaxf(acc[m][n][r] + bb, 0.f);
          const float other = __shfl_xor(vv, 1);
          if ((c & 1) == 0) {
            const uint32_t word = (uint32_t)f2bf(vv) | ((uint32_t)f2bf(other) << 16);
            *(uint32_t*)((ushort*)Cout + (size_t)(row0 + r)*NDIM + col) = word;
          }
        }
      } else if (MODE == 4) {   // K,V both head-major
        const int b_ = row0 >> 10, s = row0 & (SEQ - 1);
        const int hd = col & 255;
        const int hh = hd >> 5, d = hd & 31;
        const float bb = (col < 256) ? bias0[hd] : bias1[hd];
        ushort* dst = ((col < 256) ? (ushort*)Cout : vtb)
                    + (((size_t)(b_*NH + hh)*SEQ + s) << 5) + d;
        #pragma unroll
        for (int r = 0; r < 4; ++r) {
          const float vv = acc[m][n][r] + bb;
          const float other = __shfl_xor(vv, 1);
          if ((c & 1) == 0) {
            const uint32_t word = (uint32_t)f2bf(vv) | ((uint32_t)f2bf(other) << 16);
            *(uint32_t*)(dst + (r << 5)) = word;
          }
        }
      } else {  // MODE 3
        const int b_ = row0 >> 10, s = row0 & (SEQ - 1);
        if (col < 512) {
          const int hd = col & 255;
          const int hh = hd >> 5, d = hd & 31;
          const float bb = (col < 256) ? bias0[hd] : bias1[hd];
          ushort* dst = (ushort*)Cout + (col < 256 ? 0 : QKSTRIDE)
                      + (((size_t)(b_*NH + hh)*SEQ + s) << 5) + d;
          #pragma unroll
          for (int r = 0; r < 4; ++r) {
            const float vv = acc[m][n][r] + bb;
            const float other = __shfl_xor(vv, 1);
            if ((c & 1) == 0) {
              const uint32_t word = (uint32_t)f2bf(vv) | ((uint32_t)f2bf(other) << 16);
              *(uint32_t*)(dst + (r << 5)) = word;
            }
          }
        } else {
          // V: permuted k-slot layout. position p = g'*8 + hi*4 + rr <-> key 16*hi+4*g'+rr
          const int hd = col - 512;
          const int hh = hd >> 5, d = hd & 31;
          const float bb = bias2[hd];
          const int sg = s >> 5, a = (s & 31) >> 2;
          const int pbase = (a & 3)*8 + (a >> 2)*4;
          ushort4 w4;
          w4.x = f2bf(acc[m][n][0] + bb);
          w4.y = f2bf(acc[m][n][1] + bb);
          w4.z = f2bf(acc[m][n][2] + bb);
          w4.w = f2bf(acc[m][n][3] + bb);
          *(ushort4*)(vtb + (((size_t)((b_*NH + hh)*32 + sg)*32 + d) << 5) + pbase) = w4;
        }
      }
    }
  }
}

// ---------------- 64x64-tile accumulate GEMM (N=256), counted-vmcnt 3-buffer ----------------
template<int KDIM>
__global__ __launch_bounds__(256) void gemm64_acc(
    const ushort* __restrict__ A, const ushort* __restrict__ Bw,
    const float* __restrict__ bias, float* __restrict__ C)
{
  __shared__ ushort Al[3][64*32];
  __shared__ ushort Bl[3][64*32];
  const int bm = blockIdx.y * 64, bn = blockIdx.x * 64;
  const int tid = threadIdx.x, w = tid >> 6, lane = tid & 63;
  const int wm = w >> 1, wn = w & 1;
  const int g = lane >> 4, c = lane & 15;
  const int lrow = tid >> 2, lc8 = (tid & 3) << 3;
  const f32x4 fzero = {0.f, 0.f, 0.f, 0.f};
  f32x4 acc[2][2];
  acc[0][0] = fzero; acc[0][1] = fzero; acc[1][0] = fzero; acc[1][1] = fzero;

#define STAGE64(buf, k0)                                                       \
  {                                                                            \
    gload_lds16(A  + (size_t)(bm + lrow)*KDIM + (k0) + lc8,                    \
                &Al[buf][lrow*32 + lc8]);                                      \
    gload_lds16(Bw + (size_t)(bn + lrow)*KDIM + (k0) + lc8,                    \
                &Bl[buf][lrow*32 + lc8]);                                      \
  }

#define COMPUTE64(buf)                                                         \
  {                                                                            \
    bf16x8 af[2], bfr[2];                                                      \
    _Pragma("unroll")                                                          \
    for (int m = 0; m < 2; ++m)                                                \
      af[m] = *(const bf16x8*)&Al[buf][(wm*32 + m*16 + c)*32 + g*8];           \
    _Pragma("unroll")                                                          \
    for (int n = 0; n < 2; ++n)                                                \
      bfr[n] = *(const bf16x8*)&Bl[buf][(wn*32 + n*16 + c)*32 + g*8];          \
    _Pragma("unroll")                                                          \
    for (int m = 0; m < 2; ++m)                                                \
      _Pragma("unroll")                                                        \
      for (int n = 0; n < 2; ++n)                                              \
        acc[m][n] = __builtin_amdgcn_mfma_f32_16x16x32_bf16(af[m], bfr[n], acc[m][n], 0, 0, 0); \
  }

  STAGE64(0, 0);
  STAGE64(1, 32);
  STAGE64(2, 64);
  int buf = 0;
  for (int k0 = 0; k0 + 64 < KDIM; k0 += 32) {
    asm volatile("s_waitcnt vmcnt(4)" ::: "memory");
    __builtin_amdgcn_s_barrier();
    COMPUTE64(buf);
    asm volatile("s_waitcnt lgkmcnt(0)" ::: "memory");
    __builtin_amdgcn_s_barrier();
    if (k0 + 96 < KDIM) STAGE64(buf, k0 + 96);
    buf = (buf == 2) ? 0 : buf + 1;
  }
  asm volatile("s_waitcnt vmcnt(2)" ::: "memory");
  __builtin_amdgcn_s_barrier();
  COMPUTE64(buf);
  buf = (buf == 2) ? 0 : buf + 1;
  asm volatile("s_waitcnt vmcnt(0)" ::: "memory");
  __builtin_amdgcn_s_barrier();
  COMPUTE64(buf);
#undef STAGE64
#undef COMPUTE64

  #pragma unroll
  for (int m = 0; m < 2; ++m) {
    const int row0 = bm + wm*32 + m*16 + g*4;
    #pragma unroll
    for (int n = 0; n < 2; ++n) {
      const int col = bn + wn*32 + n*16 + c;
      const float bb = bias[col];
      #pragma unroll
      for (int r = 0; r < 4; ++r)
        C[(size_t)(row0 + r)*DIM + col] += acc[m][n][r] + bb;
    }
  }
}

// ---------------- flash attention (layer 0): 32 q-rows/block, max-free softmax ----------------
__global__ __launch_bounds__(256) void attn_mfma(
    const ushort* __restrict__ qh, const ushort* __restrict__ kh,
    const ushort* __restrict__ vph, const float* __restrict__ bm2l,
    ushort* __restrict__ O)
{
  const int bid = blockIdx.x;
  const int lin = ((bid & 7) << 8) + (bid >> 3);       // bijective (2048 % 8 == 0)
  const int tid = threadIdx.x, w = tid >> 6, lane = tid & 63;
  const int qw = lin & 31, h = (lin >> 5) & 7, b = lin >> 8;
  const int qb = qw << 5;
  const float scale2 = 0.17677669529663687f * 1.4426950408889634f;  // rsqrt(32)*log2e
  const int g = lane >> 4, c = lane & 15;
  const f32x4 fzero = {0.f, 0.f, 0.f, 0.f};
  const size_t bh = (size_t)(b*NH + h);

  const bf16x8 qf0 = *(const bf16x8*)(qh + ((bh*SEQ + qb + c)      << 5) + g*8);
  const bf16x8 qf1 = *(const bf16x8*)(qh + ((bh*SEQ + qb + 16 + c) << 5) + g*8);
  const ushort* kbase = kh  + ((bh*SEQ) << 5) + g*8;
  const ushort* vbase = vph + ((bh*SEQ) << 5) + g*8;
  const float*  bmb   = bm2l + b*SEQ;

  f32x4 oacc[2][2];
  oacc[0][0] = fzero; oacc[0][1] = fzero; oacc[1][0] = fzero; oacc[1][1] = fzero;
  float l0 = 0.f, l1 = 0.f;

  bf16x8 kfA[4], kfB[4];
  bf16x8 vfA[2][2], vfB[2][2];
  f32x4 bbA[4], bbB[4];

#define LOADT(kt, kf, vf, bb)                                                  \
  {                                                                            \
    _Pragma("unroll")                                                          \
    for (int ks = 0; ks < 4; ++ks) {                                           \
      kf[ks] = *(const bf16x8*)(kbase + (((kt) + ks*16 + c) << 5));            \
      bb[ks] = *(const f32x4*)(bmb + (kt) + ks*16 + g*4);                      \
    }                                                                          \
    _Pragma("unroll")                                                          \
    for (int ds_ = 0; ds_ < 2; ++ds_)                                          \
      _Pragma("unroll")                                                        \
      for (int sg = 0; sg < 2; ++sg)                                           \
        vf[ds_][sg] = *(const bf16x8*)(vbase +                                 \
            (((((kt) >> 5) + sg)*32 + ds_*16 + c) << 5));                      \
  }

#define ATILE(kf, vf, bb)                                                      \
  {                                                                            \
    f32x4 sf0[4], sf1[4];                                                      \
    __builtin_amdgcn_s_setprio(1);                                             \
    _Pragma("unroll")                                                          \
    for (int ks = 0; ks < 4; ++ks)                                             \
      sf0[ks] = __builtin_amdgcn_mfma_f32_16x16x32_bf16(kf[ks], qf0, fzero, 0, 0, 0); \
    _Pragma("unroll")                                                          \
    for (int ks = 0; ks < 4; ++ks)                                             \
      sf1[ks] = __builtin_amdgcn_mfma_f32_16x16x32_bf16(kf[ks], qf1, fzero, 0, 0, 0); \
    __builtin_amdgcn_s_setprio(0);                                             \
    float e0[4][4], e1[4][4];                                                  \
    _Pragma("unroll")                                                          \
    for (int ks = 0; ks < 4; ++ks)                                             \
      _Pragma("unroll")                                                        \
      for (int r = 0; r < 4; ++r) {                                            \
        e0[ks][r] = exp2_n(fmaf(sf0[ks][r], scale2, bb[ks][r]));               \
        e1[ks][r] = exp2_n(fmaf(sf1[ks][r], scale2, bb[ks][r]));               \
      }                                                                        \
    float a0 = 0.f, a1 = 0.f, a2 = 0.f, a3 = 0.f;                              \
    _Pragma("unroll")                                                          \
    for (int r = 0; r < 4; ++r) {                                              \
      a0 += e0[0][r] + e0[1][r]; a1 += e0[2][r] + e0[3][r];                    \
      a2 += e1[0][r] + e1[1][r]; a3 += e1[2][r] + e1[3][r];                    \
    }                                                                          \
    l0 += a0 + a1; l1 += a2 + a3;                                              \
    union { bf16x8 v; uint32_t u[4]; } p00, p01, p10, p11;                     \
    p00.u[0] = cvtpk(e0[0][0], e0[0][1]); p00.u[1] = cvtpk(e0[0][2], e0[0][3]);\
    p00.u[2] = cvtpk(e0[1][0], e0[1][1]); p00.u[3] = cvtpk(e0[1][2], e0[1][3]);\
    p01.u[0] = cvtpk(e0[2][0], e0[2][1]); p01.u[1] = cvtpk(e0[2][2], e0[2][3]);\
    p01.u[2] = cvtpk(e0[3][0], e0[3][1]); p01.u[3] = cvtpk(e0[3][2], e0[3][3]);\
    p10.u[0] = cvtpk(e1[0][0], e1[0][1]); p10.u[1] = cvtpk(e1[0][2], e1[0][3]);\
    p10.u[2] = cvtpk(e1[1][0], e1[1][1]); p10.u[3] = cvtpk(e1[1][2], e1[1][3]);\
    p11.u[0] = cvtpk(e1[2][0], e1[2][1]); p11.u[1] = cvtpk(e1[2][2], e1[2][3]);\
    p11.u[2] = cvtpk(e1[3][0], e1[3][1]); p11.u[3] = cvtpk(e1[3][2], e1[3][3]);\
    __builtin_amdgcn_s_setprio(1);                                             \
    oacc[0][0] = __builtin_amdgcn_mfma_f32_16x16x32_bf16(vf[0][0], p00.v, oacc[0][0], 0, 0, 0); \
    oacc[0][1] = __builtin_amdgcn_mfma_f32_16x16x32_bf16(vf[1][0], p00.v, oacc[0][1], 0, 0, 0); \
    oacc[1][0] = __builtin_amdgcn_mfma_f32_16x16x32_bf16(vf[0][0], p10.v, oacc[1][0], 0, 0, 0); \
    oacc[1][1] = __builtin_amdgcn_mfma_f32_16x16x32_bf16(vf[1][0], p10.v, oacc[1][1], 0, 0, 0); \
    oacc[0][0] = __builtin_amdgcn_mfma_f32_16x16x32_bf16(vf[0][1], p01.v, oacc[0][0], 0, 0, 0); \
    oacc[0][1] = __builtin_amdgcn_mfma_f32_16x16x32_bf16(vf[1][1], p01.v, oacc[0][1], 0, 0, 0); \
    oacc[1][0] = __builtin_amdgcn_mfma_f32_16x16x32_bf16(vf[0][1], p11.v, oacc[1][0], 0, 0, 0); \
    oacc[1][1] = __builtin_amdgcn_mfma_f32_16x16x32_bf16(vf[1][1], p11.v, oacc[1][1], 0, 0, 0); \
    __builtin_amdgcn_s_setprio(0);                                             \
  }

  const int kt0 = w << 8;
  LOADT(kt0, kfA, vfA, bbA);
  LOADT(kt0 + 64, kfB, vfB, bbB);
  ATILE(kfA, vfA, bbA);
  LOADT(kt0 + 128, kfA, vfA, bbA);
  ATILE(kfB, vfB, bbB);
  LOADT(kt0 + 192, kfB, vfB, bbB);
  ATILE(kfA, vfA, bbA);
  ATILE(kfB, vfB, bbB);
#undef LOADT
#undef ATILE

  __shared__ float Lo[4][64][19];
  #pragma unroll
  for (int q = 0; q < 2; ++q)
    #pragma unroll
    for (int ds_ = 0; ds_ < 2; ++ds_)
      #pragma unroll
      for (int i = 0; i < 4; ++i)
        Lo[w][lane][q*8 + ds_*4 + i] = oacc[q][ds_][i];
  Lo[w][lane][16] = l0;
  Lo[w][lane][17] = l1;
  __syncthreads();
  if (w < 2) {
    const int q = w;
    float o[8] = {0.f,0.f,0.f,0.f,0.f,0.f,0.f,0.f};
    float ls = 0.f;
    #pragma unroll
    for (int ww = 0; ww < 4; ++ww) {
      ls += Lo[ww][lane][16 + q];
      #pragma unroll
      for (int i = 0; i < 8; ++i) o[i] += Lo[ww][lane][q*8 + i];
    }
    ls += __shfl_xor(ls, 16);
    ls += __shfl_xor(ls, 32);
    const float inv = 1.f / ls;
    ushort* orow = O + (size_t)(b*SEQ + qb + q*16 + c)*DIM + h*32 + g*4;
    const uint32_t w0 = (uint32_t)f2bf(o[0]*inv) | ((uint32_t)f2bf(o[1]*inv) << 16);
    const uint32_t w1 = (uint32_t)f2bf(o[2]*inv) | ((uint32_t)f2bf(o[3]*inv) << 16);
    const uint32_t w2 = (uint32_t)f2bf(o[4]*inv) | ((uint32_t)f2bf(o[5]*inv) << 16);
    const uint32_t w3 = (uint32_t)f2bf(o[6]*inv) | ((uint32_t)f2bf(o[7]*inv) << 16);
    *(uint32_t*)(orow)      = w0;
    *(uint32_t*)(orow + 2)  = w1;
    *(uint32_t*)(orow + 16) = w2;
    *(uint32_t*)(orow + 18) = w3;
  }
}

// ---------------- layer-2 tail: Q for row 0 of each batch (GEMV) ----------------
__global__ __launch_bounds__(256) void q8_kernel(
    const ushort* __restrict__ x2b, const ushort* __restrict__ Wq1,
    const float* __restrict__ bq1, float* __restrict__ q8f)
{
  const int b = blockIdx.x, tid = threadIdx.x;
  __shared__ float xrow[256];
  xrow[tid] = bf2f(x2b[(size_t)(b*SEQ)*DIM + tid]);
  __syncthreads();
  const ushort* wrow = Wq1 + (size_t)tid*DIM;
  float acc = bq1[tid];
  #pragma unroll
  for (int k8 = 0; k8 < 32; ++k8) {
    const bf16x8 wv = *(const bf16x8*)(wrow + k8*8);
    #pragma unroll
    for (int j = 0; j < 8; ++j)
      acc = fmaf(bf2f((ushort)wv[j]), xrow[k8*8 + j], acc);
  }
  q8f[b*DIM + tid] = acc;
}

// ---------------- layer-2 tail: decode attention (8 q-rows total) ----------------
// grid 64 = (b,h); K,V head-major; max-free base-2 softmax; f32 throughout.
__global__ __launch_bounds__(256) void attn_decode(
    const float* __restrict__ q8f, const ushort* __restrict__ kh,
    const ushort* __restrict__ vh, const float* __restrict__ bm2l,
    float* __restrict__ obuf)
{
  const int b = blockIdx.x >> 3, h = blockIdx.x & 7;
  const int tid = threadIdx.x;
  const float scale2 = 0.17677669529663687f * 1.4426950408889634f;
  __shared__ float qv[32];
  if (tid < 32) qv[tid] = q8f[b*DIM + h*32 + tid];
  __syncthreads();
  const ushort* kb = kh + (((size_t)(b*NH + h))*SEQ << 5);
  const ushort* vb = vh + (((size_t)(b*NH + h))*SEQ << 5);
  const float* bias = bm2l + b*SEQ;
  float o[32];
  #pragma unroll
  for (int d = 0; d < 32; ++d) o[d] = 0.f;
  float lsum = 0.f;
  #pragma unroll
  for (int kk = 0; kk < 4; ++kk) {
    const int key = kk*256 + tid;
    const ushort* kr = kb + (key << 5);
    float dot = 0.f;
    #pragma unroll
    for (int i = 0; i < 4; ++i) {
      const bf16x8 kv8 = *(const bf16x8*)(kr + i*8);
      #pragma unroll
      for (int j = 0; j < 8; ++j)
        dot = fmaf(bf2f((ushort)kv8[j]), qv[i*8 + j], dot);
    }
    const float e = exp2_n(fmaf(dot, scale2, bias[key]));
    lsum += e;
    const ushort* vr = vb + (key << 5);
    #pragma unroll
    for (int i = 0; i < 4; ++i) {
      const bf16x8 vv8 = *(const bf16x8*)(vr + i*8);
      #pragma unroll
      for (int j = 0; j < 8; ++j)
        o[i*8 + j] = fmaf(e, bf2f((ushort)vv8[j]), o[i*8 + j]);
    }
  }
  __shared__ float red[256][33];
  #pragma unroll
  for (int d = 0; d < 32; ++d) red[tid][d] = o[d];
  red[tid][32] = lsum;
  __syncthreads();
  __shared__ float fin[33];
  if (tid < 33) {
    float s = 0.f;
    for (int t = 0; t < 256; ++t) s += red[t][tid];
    fin[tid] = s;
  }
  __syncthreads();
  if (tid < 32)
    obuf[b*DIM + h*32 + tid] = fin[tid] / fin[32];
}

// ---------------- layer-2 tail: Wo proj + residual (row 0) + LN2 -> bf16 ----------------
__global__ __launch_bounds__(256) void tail_wo_ln(
    const float* __restrict__ obuf, const ushort* __restrict__ WoT1,
    const float* __restrict__ bo1, const float* __restrict__ g21,
    const float* __restrict__ be21, float* __restrict__ x,
    ushort* __restrict__ t2b)
{
  const int b = blockIdx.x, tid = threadIdx.x;
  const int wave = tid >> 6, lane = tid & 63;
  __shared__ float orow[256];
  __shared__ float red[2][4];
  orow[tid] = obuf[b*DIM + tid];
  __syncthreads();
  const ushort* wrow = WoT1 + (size_t)tid*DIM;
  float acc = bo1[tid];
  #pragma unroll
  for (int k8 = 0; k8 < 32; ++k8) {
    const bf16x8 wv = *(const bf16x8*)(wrow + k8*8);
    #pragma unroll
    for (int j = 0; j < 8; ++j)
      acc = fmaf(bf2f((ushort)wv[j]), orow[k8*8 + j], acc);
  }
  float* xp = x + (size_t)(b*SEQ)*DIM + tid;
  const float newx = *xp + acc;
  *xp = newx;
  // LN2
  float sm = newx;
  #pragma unroll
  for (int o = 32; o >= 1; o >>= 1) sm += __shfl_xor(sm, o);
  if (lane == 0) red[0][wave] = sm;
  __syncthreads();
  const float mean = (red[0][0]+red[0][1]+red[0][2]+red[0][3]) * (1.f/256.f);
  const float dv = newx - mean;
  float q = dv * dv;
  #pragma unroll
  for (int o = 32; o >= 1; o >>= 1) q += __shfl_xor(q, o);
  if (lane == 0) red[1][wave] = q;
  __syncthreads();
  const float var = (red[1][0]+red[1][1]+red[1][2]+red[1][3]) * (1.f/256.f);
  const float rs = rsqrtf(var + 1e-5f);
  t2b[b*DIM + tid] = f2bf(dv*rs*g21[tid] + be21[tid]);
}

// ---------------- layer-2 tail: FF1 (row 0) ----------------
__global__ __launch_bounds__(256) void tail_ff1(
    const ushort* __restrict__ t2b, const ushort* __restrict__ W1T1,
    const float* __restrict__ b11, ushort* __restrict__ midr)
{
  const int b = blockIdx.x >> 2, c4 = blockIdx.x & 3, tid = threadIdx.x;
  __shared__ float trow[256];
  trow[tid] = bf2f(t2b[b*DIM + tid]);
  __syncthreads();
  const int col = c4*256 + tid;
  const ushort* wrow = W1T1 + (size_t)col*DIM;
  float acc = b11[col];
  #pragma unroll
  for (int k8 = 0; k8 < 32; ++k8) {
    const bf16x8 wv = *(const bf16x8*)(wrow + k8*8);
    #pragma unroll
    for (int j = 0; j < 8; ++j)
      acc = fmaf(bf2f((ushort)wv[j]), trow[k8*8 + j], acc);
  }
  midr[b*FFD + col] = f2bf(fmaxf(acc, 0.f));
}

// ---------------- layer-2 tail: FF2 + residual (row 0) ----------------
__global__ __launch_bounds__(256) void tail_ff2(
    const ushort* __restrict__ midr, const ushort* __restrict__ W2T1,
    const float* __restrict__ b21, float* __restrict__ x)
{
  const int b = blockIdx.x, tid = threadIdx.x;
  __shared__ float mrow[1024];
  #pragma unroll
  for (int i = 0; i < 4; ++i)
    mrow[i*256 + tid] = bf2f(midr[b*FFD + i*256 + tid]);
  __syncthreads();
  const ushort* wrow = W2T1 + (size_t)tid*FFD;
  float acc = b21[tid];
  #pragma unroll
  for (int k8 = 0; k8 < 128; ++k8) {
    const bf16x8 wv = *(const bf16x8*)(wrow + k8*8);
    #pragma unroll
    for (int j = 0; j < 8; ++j)
      acc = fmaf(bf2f((ushort)wv[j]), mrow[k8*8 + j], acc);
  }
  x[(size_t)(b*SEQ)*DIM + tid] += acc;
}

// ---------------- final LN (row 0 per batch) + classifier ----------------
__global__ __launch_bounds__(256) void cls_kernel(
    const float* __restrict__ x, const float* __restrict__ gf,
    const float* __restrict__ bf, const float* __restrict__ Wc,
    const float* __restrict__ bc, float* __restrict__ out)
{
  const int b = blockIdx.x;
  const int tid = threadIdx.x;
  const int wave = tid >> 6, lane = tid & 63;
  const float* xr = x + (size_t)b * SEQ * DIM;
  const float v = xr[tid];
  __shared__ float redm[4], redv[4], redc[4][4];
  float s = v;
  #pragma unroll
  for (int o = 32; o >= 1; o >>= 1) s += __shfl_xor(s, o);
  if (lane == 0) redm[wave] = s;
  __syncthreads();
  const float mean = (redm[0]+redm[1]+redm[2]+redm[3]) * (1.f/256.f);
  const float dv = v - mean;
  float q = dv * dv;
  #pragma unroll
  for (int o = 32; o >= 1; o >>= 1) q += __shfl_xor(q, o);
  if (lane == 0) redv[wave] = q;
  __syncthreads();
  const float var = (redv[0]+redv[1]+redv[2]+redv[3]) * (1.f/256.f);
  const float rs = rsqrtf(var + 1e-5f);
  const float yn = dv*rs*gf[tid] + bf[tid];
  float pc[4];
  #pragma unroll
  for (int cc = 0; cc < 4; ++cc) pc[cc] = yn * Wc[tid*4 + cc];
  #pragma unroll
  for (int cc = 0; cc < 4; ++cc) {
    #pragma unroll
    for (int o = 32; o >= 1; o >>= 1) pc[cc] += __shfl_xor(pc[cc], o);
  }
  if (lane == 0) {
    #pragma unroll
    for (int cc = 0; cc < 4; ++cc) redc[wave][cc] = pc[cc];
  }
  __syncthreads();
  if (tid < 4)
    out[b*4 + tid] = redc[0][tid] + redc[1][tid] + redc[2][tid] + redc[3][tid] + bc[tid];
}

extern "C" void kernel_launch(void* const* d_in, const int* in_sizes, int n_in,
                              void* d_out, int out_size, void* d_ws, size_t ws_size,
                              hipStream_t stream)
{
  const int*   ids    = (const int*)d_in[0];
  const int*   ngrams = (const int*)d_in[1];
  const float* tfidf  = (const float*)d_in[2];
  const float* emb    = (const float*)d_in[3];
  const float* pos    = (const float*)d_in[4];
  const float* bucket = (const float*)d_in[5];
  const float* Wq = (const float*)d_in[6];  const float* bq = (const float*)d_in[7];
  const float* Wk = (const float*)d_in[8];  const float* bk = (const float*)d_in[9];
  const float* Wv = (const float*)d_in[10]; const float* bv = (const float*)d_in[11];
  const float* Wo = (const float*)d_in[12]; const float* bo = (const float*)d_in[13];
  const float* g1 = (const float*)d_in[14]; const float* be1= (const float*)d_in[15];
  const float* g2 = (const float*)d_in[16]; const float* be2= (const float*)d_in[17];
  const float* W1 = (const float*)d_in[18]; const float* b1 = (const float*)d_in[19];
  const float* W2 = (const float*)d_in[20]; const float* b2 = (const float*)d_in[21];
  const float* alpha = (const float*)d_in[22];
  const float* gf = (const float*)d_in[23]; const float* bf = (const float*)d_in[24];
  const float* Wc = (const float*)d_in[25]; const float* bc = (const float*)d_in[26];

  uint8_t* base = (uint8_t*)d_ws;
  float*  x      = (float*)  base;                  //  8,388,608
  ushort* x2b    = (ushort*)(base + 8388608);       //  4,194,304
  ushort* qkh    = (ushort*)(base + 12582912);      //  8,388,608 (Q head-major, K at +QKSTRIDE)
  ushort* vtb    = (ushort*)(base + 20971520);      //  4,194,304 (V permuted l0 / V head-major l1)
  ushort* attb   = (ushort*)(base + 25165824);      //  4,194,304 (l0 attn out; l1 tail scratch)
  ushort* midb   = (ushort*)(base + 29360128);      // 16,777,216
  float*  bm2    = (float*) (base + 46137344);      //     65,536 (2 layers)
  ushort* WqkvT  = (ushort*)(base + 46202880);      //    786,432
  ushort* WoT    = (ushort*)(base + 46989312);      //    262,144
  ushort* W1T    = (ushort*)(base + 47251456);      //  1,048,576
  ushort* W2T    = (ushort*)(base + 48300032);      //  1,048,576  -> 49,348,608 total

  // layer-2 tail scratch carved from attb space (dead in layer 1 path)
  float*  q8f  = (float*)attb;                      // 8*256 f32
  float*  obuf = (float*)(base + 25165824 + 8192);  // 8*256 f32
  ushort* t2b  = (ushort*)(base + 25165824 + 16384);// 8*256 bf16
  ushort* midr = (ushort*)(base + 25165824 + 20480);// 8*1024 bf16

  TDescs td;
  for (int l = 0; l < NL; ++l) {
    td.d[6*l+0] = { Wq + (size_t)l*DIM*DIM, WqkvT + (size_t)l*768*DIM +   0*DIM, DIM, DIM };
    td.d[6*l+1] = { Wk + (size_t)l*DIM*DIM, WqkvT + (size_t)l*768*DIM + 256*DIM, DIM, DIM };
    td.d[6*l+2] = { Wv + (size_t)l*DIM*DIM, WqkvT + (size_t)l*768*DIM + 512*DIM, DIM, DIM };
    td.d[6*l+3] = { Wo + (size_t)l*DIM*DIM, WoT  + (size_t)l*DIM*DIM,  DIM, DIM };
    td.d[6*l+4] = { W1 + (size_t)l*DIM*FFD, W1T  + (size_t)l*FFD*DIM,  DIM, FFD };
    td.d[6*l+5] = { W2 + (size_t)l*FFD*DIM, W2T  + (size_t)l*DIM*FFD,  FFD, DIM };
  }
  transpose_conv<<<dim3(32, 32, 12), 256, 0, stream>>>(td);

  embed_ln_kernel<<<TOK, 256, 0, stream>>>(
      ids, ngrams, tfidf, emb, pos, bucket, alpha, g1, be1, x, x2b, bm2);

  const dim3 gqkv(6, TOK/64), gkv(4, TOK/64), gff1(8, TOK/64), g64(4, TOK/64);

  // ---------- layer 0: full pipeline ----------
  gemm_mfma<256, 768, 3><<<gqkv, 256, 0, stream>>>(
      x2b, WqkvT, bq, bk, bv, qkh, vtb);
  attn_mfma<<<2048, 256, 0, stream>>>(qkh, qkh + QKSTRIDE, vtb, bm2, attb);
  gemm64_acc<256><<<g64, 256, 0, stream>>>(attb, WoT, bo, x);
  ln_bf16<<<TOK/4, 256, 0, stream>>>(x, g2, be2, x2b);
  gemm_mfma<256, 1024, 1><<<gff1, 256, 0, stream>>>(
      x2b, W1T, b1, nullptr, nullptr, midb, nullptr);
  gemm64_acc<1024><<<g64, 256, 0, stream>>>(midb, W2T, b2, x);

  // ---------- layer 1: only row 0 per batch feeds the output ----------
  ln_bf16<<<TOK/4, 256, 0, stream>>>(x, g1 + DIM, be1 + DIM, x2b);
  // K,V (all positions, head-major); V into vtb reused head-major
  gemm_mfma<256, 512, 4><<<gkv, 256, 0, stream>>>(
      x2b, WqkvT + (size_t)768*DIM + 256*DIM, bk + DIM, bv + DIM, nullptr,
      qkh + QKSTRIDE, vtb);
  // Q only for row 0 of each batch
  q8_kernel<<<8, 256, 0, stream>>>(x2b, WqkvT + (size_t)768*DIM, bq + DIM, q8f);
  attn_decode<<<64, 256, 0, stream>>>(q8f, qkh + QKSTRIDE, vtb, bm2 + TOK, obuf);
  tail_wo_ln<<<8, 256, 0, stream>>>(obuf, WoT + DIM*DIM, bo + DIM,
                                    g2 + DIM, be2 + DIM, x, t2b);
  tail_ff1<<<32, 256, 0, stream>>>(t2b, W1T + FFD*DIM, b1 + FFD, midr);
  tail_ff2<<<8, 256, 0, stream>>>(midr, W2T + DIM*FFD, b2 + DIM, x);

  cls_kernel<<<8, 256, 0, stream>>>(x, gf, bf, Wc, bc, (float*)d_out);
}